// Round 7
// baseline (121.651 us; speedup 1.0000x reference)
//
#include <hip/hip_runtime.h>

// PastFutureContext: B=8, N=1024, d=h=512 — bf16 MFMA, ring-4 counted-vmcnt
// (graduated waits, latency tolerance = 2 iters), fused launches (4 total).
// Math: out = sp_i*(trilW @ GaT^T) + sf_i*(triuW @ GcT^T) + Gb, where
//   W[b]    = proj[b] @ F[b]^T        (proj = F@W1^T + b1)
//   GacT[b] = [W2a;W2c] @ F[b]^T * sm_j
//   Gb      = F @ W2b^T + b2   — written straight into out (f32); tri does RMW.
// Launches: prep (scales+cvt+prepw) -> PGGA (pg ∪ gact) -> weight -> tri.
// LDS swizzle (verified r5: conflicts=0): lane l stages global col-slot
// ((l&3)-(l>>3))&3; read slot q(r,c0)=(c0+(r>>1))&3.

constexpr int BATCH = 8;
constexpr int SEQ   = 1024;
constexpr int DIM   = 512;
constexpr int HID   = 512;

typedef __bf16 bf16_t;
typedef bf16_t bf16x8 __attribute__((ext_vector_type(8)));
typedef float  f32x4  __attribute__((ext_vector_type(4)));
typedef float  f4     __attribute__((ext_vector_type(4)));

typedef __attribute__((address_space(1))) void gv_t;
typedef __attribute__((address_space(3))) void lv_t;

__device__ __forceinline__ void gload16(const bf16_t* g, bf16_t* l) {
  __builtin_amdgcn_global_load_lds((gv_t*)g, (lv_t*)l, 16, 0, 0);
}

#define WAIT6() asm volatile("s_waitcnt vmcnt(6)" ::: "memory")
#define WAIT3() asm volatile("s_waitcnt vmcnt(3)" ::: "memory")
#define WAIT0() asm volatile("s_waitcnt vmcnt(0)" ::: "memory")
#define BAR()   { __builtin_amdgcn_s_barrier(); __builtin_amdgcn_sched_barrier(0); }

// Stage a [ROWS x 32] bf16 tile (row-major, ld elems) into LDS as ROWS/16
// chunks of 512 elems. Lane l lands at elem l*8 of its chunk (linear dest).
// Pre-swizzled global source (see header).
template <int ROWS>
__device__ __forceinline__ void stage(const bf16_t* g, int ld, bf16_t* lds,
                                      int w, int lane) {
  const int r0 = lane >> 2;
  const int kc = ((((lane & 3) - (lane >> 3)) & 3)) * 8;
#pragma unroll
  for (int i = 0; i < ROWS / 64; ++i) {
    const int s = w * (ROWS / 64) + i;
    gload16(g + (size_t)(s * 16 + r0) * ld + kc, lds + s * 512);
  }
}

// read-side swizzled elem offset within a 16-row chunk (row fr, global slot c0)
__device__ __forceinline__ int swz8(int fr, int c0) {
  return (((fr << 2) | ((c0 + (fr >> 1)) & 3)) << 3);
}

// ---- fused prep: cvt F (blocks 0..2047) | prepw (2048..2559) | scales (2560..2567)
__global__ __launch_bounds__(256) void prep_kernel(
    const float* __restrict__ F, const int* __restrict__ smask,
    const float* __restrict__ W1, const float* __restrict__ W2,
    bf16_t* __restrict__ Fbf, bf16_t* __restrict__ Wpg, bf16_t* __restrict__ W2ac,
    float* __restrict__ sp, float* __restrict__ sf) {
  const int bid = blockIdx.x, tid = threadIdx.x;
  if (bid < 2048) {                       // cvt: 8 f32 -> bf16 per thread
    const int i = bid * 256 + tid;        // i < 524288
    const f4* p = (const f4*)(F + (size_t)i * 8);
    f4 v0 = p[0], v1 = p[1];
    bf16x8 o;
    o[0] = (bf16_t)v0[0]; o[1] = (bf16_t)v0[1]; o[2] = (bf16_t)v0[2]; o[3] = (bf16_t)v0[3];
    o[4] = (bf16_t)v1[0]; o[5] = (bf16_t)v1[1]; o[6] = (bf16_t)v1[2]; o[7] = (bf16_t)v1[3];
    *(bf16x8*)(Fbf + (size_t)i * 8) = o;
    return;
  }
  if (bid < 2560) {                       // prepw: restack W1/W2 -> Wpg, W2ac
    const int idx = (bid - 2048) * 256 + tid;
    const int r = idx >> 6, c8 = (idx & 63) * 8;
    const float* src;
    bf16_t* dst;
    if (r < 512)       { src = W1 + (size_t)r * 512 + c8;                  dst = Wpg  + (size_t)r * 512 + c8; }
    else if (r < 1024) { src = W2 + (size_t)(r - 512) * 1536 + 512 + c8;   dst = Wpg  + (size_t)r * 512 + c8; }
    else if (r < 1536) { src = W2 + (size_t)(r - 1024) * 1536 + c8;        dst = W2ac + (size_t)(r - 1024) * 512 + c8; }
    else               { src = W2 + (size_t)(r - 1536) * 1536 + 1024 + c8; dst = W2ac + (size_t)(r - 1024) * 512 + c8; }
    f4 v0 = *(const f4*)src, v1 = *(const f4*)(src + 4);
    bf16x8 o;
    o[0] = (bf16_t)v0[0]; o[1] = (bf16_t)v0[1]; o[2] = (bf16_t)v0[2]; o[3] = (bf16_t)v0[3];
    o[4] = (bf16_t)v1[0]; o[5] = (bf16_t)v1[1]; o[6] = (bf16_t)v1[2]; o[7] = (bf16_t)v1[3];
    *(bf16x8*)dst = o;
    return;
  }
  // scales: batch = bid - 2560; 256 thr x 4 elems, wave scan + block combine
  const int b = bid - 2560;
  const int4 v4 = ((const int4*)(smask + b * SEQ))[tid];
  const int tsum = v4.x + v4.y + v4.z + v4.w;
  int x = tsum;
#pragma unroll
  for (int o = 1; o < 64; o <<= 1) {
    int y = __shfl_up(x, o, 64);
    if ((tid & 63) >= o) x += y;
  }
  __shared__ int wsum[4], wpre[5];
  if ((tid & 63) == 63) wsum[tid >> 6] = x;
  __syncthreads();
  if (tid == 0) { int c = 0; for (int w = 0; w < 4; ++w) { wpre[w] = c; c += wsum[w]; } wpre[4] = c; }
  __syncthreads();
  const int excl = (x - tsum) + wpre[tid >> 6];   // elems before this thread's 4
  const float tot = (float)wpre[4];
  f4 spv, sfv;
  int pre = excl;
  const int e[4] = {v4.x, v4.y, v4.z, v4.w};
#pragma unroll
  for (int i = 0; i < 4; ++i) {
    const float P  = (float)pre;
    const float Fu = tot - (float)pre - (float)e[i];
    spv[i] = e[i] ? 1.f / (P  + 1e-8f) : 0.f;
    sfv[i] = e[i] ? 1.f / (Fu + 1e-8f) : 0.f;
    pre += e[i];
  }
  ((f4*)(sp + b * SEQ))[tid] = spv;
  ((f4*)(sf + b * SEQ))[tid] = sfv;
}

// ---- ring-4 counted-vmcnt 128x64 GEMM core (wave 64x32, acc 4x2) -------------
// 3 loads/iter/thread; prologue 3 tiles (9 loads); wait vmcnt(6) = oldest tile
// landed, 2 tiles in flight across the barrier. Graduated epilogue 6/3/0.
__device__ __forceinline__ void gemm_ring(
    const bf16_t* __restrict__ A, int lda, const bf16_t* __restrict__ Bt, int ldb,
    int K, bf16_t* As, bf16_t* Bs, f32x4 acc[4][2],
    int w, int lane, int qoff, int mw, int nw) {
  const int NT = K / 32;
#pragma unroll
  for (int p = 0; p < 3; ++p) {
    stage<128>(A + p * 32, lda, As + p * 4096, w, lane);
    stage<64>(Bt + p * 32, ldb, Bs + p * 2048, w, lane);
  }
  WAIT6();
  BAR();
  for (int k = 0; k < NT; ++k) {
    const int cur = k & 3;
    if (k + 3 < NT) {
      const int nx = (k + 3) & 3;
      stage<128>(A  + (k + 3) * 32, lda, As + nx * 4096, w, lane);
      stage<64>(Bt + (k + 3) * 32, ldb, Bs + nx * 2048, w, lane);
    }
    const bf16_t* ab = As + cur * 4096 + (mw >> 4) * 512 + qoff;
    const bf16_t* bb = Bs + cur * 2048 + (nw >> 4) * 512 + qoff;
    bf16x8 a[4], b[2];
#pragma unroll
    for (int s = 0; s < 4; ++s) a[s] = *(const bf16x8*)&ab[s * 512];
#pragma unroll
    for (int t = 0; t < 2; ++t) b[t] = *(const bf16x8*)&bb[t * 512];
#pragma unroll
    for (int s = 0; s < 4; ++s)
#pragma unroll
      for (int t = 0; t < 2; ++t)
        acc[s][t] = __builtin_amdgcn_mfma_f32_16x16x32_bf16(a[s], b[t], acc[s][t], 0, 0, 0);
    if (k + 3 < NT)      { WAIT6(); BAR(); }
    else if (k + 2 < NT) { WAIT3(); BAR(); }
    else if (k + 1 < NT) { WAIT0(); BAR(); }
  }
}

// ---- PGGA: union grid — blocks [0,1024): pg; [1024,2048): gact ---------------
__global__ __launch_bounds__(256) void pgga_mfma(
    const bf16_t* __restrict__ Fbf, const bf16_t* __restrict__ Wpg,
    const bf16_t* __restrict__ W2ac, const int* __restrict__ smask,
    const float* __restrict__ b1, const float* __restrict__ b2,
    bf16_t* __restrict__ projbf, float* __restrict__ out,
    bf16_t* __restrict__ GacT) {
  __shared__ bf16_t As[4 * 4096], Bs[4 * 2048];
  const int tid = threadIdx.x;
  const int w = tid >> 6, lane = tid & 63;
  const int fr = lane & 15;
  const int qoff = swz8(fr, lane >> 4);
  const int mw = (w >> 1) * 64, nw = (w & 1) * 32;
  const int cr = (lane >> 4) * 4, cc = lane & 15;
  const int bid = blockIdx.x;
  f32x4 acc[4][2] = {};
  if (bid < 1024) {
    // pg: [proj | Gb] = F @ [W1;W2b]^T + [b1;b2]
    const int m0 = (bid >> 4) * 128, n0 = (bid & 15) * 64;
    gemm_ring(Fbf + (size_t)m0 * DIM, DIM, Wpg + (size_t)n0 * DIM, DIM, DIM,
              As, Bs, acc, w, lane, qoff, mw, nw);
    if (n0 < 512) {
#pragma unroll
      for (int s = 0; s < 4; ++s)
#pragma unroll
        for (int t = 0; t < 2; ++t) {
          const int col = n0 + nw + t * 16 + cc;
          const float bv = b1[col];
#pragma unroll
          for (int r = 0; r < 4; ++r)
            projbf[(size_t)(m0 + mw + s * 16 + cr + r) * HID + col] = (bf16_t)(acc[s][t][r] + bv);
        }
    } else {
#pragma unroll
      for (int s = 0; s < 4; ++s)
#pragma unroll
        for (int t = 0; t < 2; ++t) {
          const int col = (n0 - 512) + nw + t * 16 + cc;
          const float bv = b2[col];
#pragma unroll
          for (int r = 0; r < 4; ++r)
            out[(size_t)(m0 + mw + s * 16 + cr + r) * HID + col] = acc[s][t][r] + bv;
        }
    }
  } else {
    // gact: GacT[b][m][j] = ([W2a;W2c] @ F[b]^T)[m][j] * sm_j
    const int q = bid - 1024;
    const int b = q >> 7, r7 = q & 127;
    const int m0 = (r7 >> 4) * 128, n0 = (r7 & 15) * 64;
    const bf16_t* Bt = Fbf + (size_t)b * SEQ * DIM;
    gemm_ring(W2ac + (size_t)m0 * DIM, DIM, Bt + (size_t)n0 * DIM, DIM, DIM,
              As, Bs, acc, w, lane, qoff, mw, nw);
    bf16_t* C = GacT + (size_t)b * SEQ * SEQ;
#pragma unroll
    for (int s = 0; s < 4; ++s)
#pragma unroll
      for (int t = 0; t < 2; ++t) {
        const int j = n0 + nw + t * 16 + cc;
        const float smj = (float)smask[b * SEQ + j];
#pragma unroll
        for (int r = 0; r < 4; ++r)
          C[(size_t)(m0 + mw + s * 16 + cr + r) * SEQ + j] = (bf16_t)(acc[s][t][r] * smj);
      }
  }
}

// ---- weight[b] = proj[b] @ F[b]^T ---------------------------------------------
__global__ __launch_bounds__(256) void weight_mfma(
    const bf16_t* __restrict__ projbf, const bf16_t* __restrict__ Fbf,
    bf16_t* __restrict__ wbuf, int b0) {
  __shared__ bf16_t As[4 * 4096], Bs[4 * 2048];
  const int tid = threadIdx.x;
  const int w = tid >> 6, lane = tid & 63;
  const int fr = lane & 15;
  const int qoff = swz8(fr, lane >> 4);
  const int mw = (w >> 1) * 64, nw = (w & 1) * 32;
  const int cr = (lane >> 4) * 4, cc = lane & 15;
  const int b = b0 + blockIdx.z;
  const bf16_t* A  = projbf + (size_t)b * SEQ * DIM;
  const bf16_t* Bt = Fbf    + (size_t)b * SEQ * DIM;
  bf16_t* C = wbuf + (size_t)blockIdx.z * SEQ * SEQ;
  const int m0 = blockIdx.y * 128, n0 = blockIdx.x * 64;
  f32x4 acc[4][2] = {};
  gemm_ring(A + (size_t)m0 * DIM, DIM, Bt + (size_t)n0 * DIM, DIM, DIM,
            As, Bs, acc, w, lane, qoff, mw, nw);
#pragma unroll
  for (int s = 0; s < 4; ++s)
#pragma unroll
    for (int t = 0; t < 2; ++t)
#pragma unroll
      for (int r = 0; r < 4; ++r)
        C[(size_t)(m0 + mw + s * 16 + cr + r) * SEQ + n0 + nw + t * 16 + cc] = (bf16_t)acc[s][t][r];
}

// ---- tri — out += sp*(trilW @ GaT^T) + sf*(triuW @ GcT^T) ---------------------
// block 64(i) x 64(n); waves 2x2 (32x32); ring-4, 3 loads/iter.
__global__ __launch_bounds__(256) void tri_mfma(
    const bf16_t* __restrict__ wbuf, const bf16_t* __restrict__ GacT,
    const float* __restrict__ scaleP, const float* __restrict__ scaleF,
    float* __restrict__ out, int b0) {
  __shared__ bf16_t As[4 * 2048], BPs[4 * 2048], BFs[4 * 2048];
  const int tid = threadIdx.x;
  const int w = tid >> 6, lane = tid & 63;
  const int fr = lane & 15, fk = (lane >> 4) * 8;
  const int qoff = swz8(fr, lane >> 4);
  const int mw = (w >> 1) * 32, nw2 = (w & 1) * 32;
  const int cr = (lane >> 4) * 4, cc = lane & 15;
  const int b = b0 + blockIdx.z;
  const bf16_t* A    = wbuf + (size_t)blockIdx.z * SEQ * SEQ;
  const bf16_t* GaTp = GacT + (size_t)b * SEQ * SEQ + (size_t)(blockIdx.x * 64) * SEQ;
  const bf16_t* GaTf = GaTp + (size_t)512 * SEQ;
  const int i0 = blockIdx.y * 64;
  f32x4 accP[2][2] = {}, accF[2][2] = {};
  const bf16_t* Arow = A + (size_t)i0 * SEQ;
#pragma unroll
  for (int p = 0; p < 3; ++p) {
    stage<64>(Arow + p * 32, SEQ, As  + p * 2048, w, lane);
    stage<64>(GaTp + p * 32, SEQ, BPs + p * 2048, w, lane);
    stage<64>(GaTf + p * 32, SEQ, BFs + p * 2048, w, lane);
  }
  WAIT6();
  BAR();
  const int NT = SEQ / 32;
  for (int kt = 0; kt < NT; ++kt) {
    const int j0 = kt * 32;
    const int cur = kt & 3;
    if (kt + 3 < NT) {
      const int nx = (kt + 3) & 3;
      const int jn = j0 + 96;
      stage<64>(Arow + jn, SEQ, As  + nx * 2048, w, lane);
      stage<64>(GaTp + jn, SEQ, BPs + nx * 2048, w, lane);
      stage<64>(GaTf + jn, SEQ, BFs + nx * 2048, w, lane);
    }
    const bool wP = (j0 < i0 + mw + 31);      // any s has pAny
    const bool wF = (j0 + 31 > i0 + mw);      // any s has fAny
    if (wP || wF) {
      const bf16_t* abase  = As  + cur * 2048 + (mw >> 4) * 512 + qoff;
      const bf16_t* bpbase = BPs + cur * 2048 + (nw2 >> 4) * 512 + qoff;
      const bf16_t* bfbase = BFs + cur * 2048 + (nw2 >> 4) * 512 + qoff;
      bf16x8 bP[2], bF[2];
#pragma unroll
      for (int t = 0; t < 2; ++t) {
        if (wP) bP[t] = *(const bf16x8*)&bpbase[t * 512];
        if (wF) bF[t] = *(const bf16x8*)&bfbase[t * 512];
      }
#pragma unroll
      for (int s = 0; s < 2; ++s) {
        const int rlo = i0 + mw + s * 16;
        const bool pAny = (j0 < rlo + 15), pFull = (j0 + 31 < rlo);
        const bool fAny = (j0 + 31 > rlo), fFull = (j0 > rlo + 15);
        if (!pAny && !fAny) continue;
        const bf16x8 a = *(const bf16x8*)&abase[s * 512];
        if (pFull) {
#pragma unroll
          for (int t = 0; t < 2; ++t)
            accP[s][t] = __builtin_amdgcn_mfma_f32_16x16x32_bf16(a, bP[t], accP[s][t], 0, 0, 0);
        } else if (pAny) {
          const int cut = (rlo + fr) - (j0 + fk);     // keep e < cut  (j < i)
          bf16x8 ap = a;
#pragma unroll
          for (int e = 0; e < 8; ++e) if (e >= cut) ap[e] = (bf16_t)0.f;
#pragma unroll
          for (int t = 0; t < 2; ++t)
            accP[s][t] = __builtin_amdgcn_mfma_f32_16x16x32_bf16(ap, bP[t], accP[s][t], 0, 0, 0);
        }
        if (fFull) {
#pragma unroll
          for (int t = 0; t < 2; ++t)
            accF[s][t] = __builtin_amdgcn_mfma_f32_16x16x32_bf16(a, bF[t], accF[s][t], 0, 0, 0);
        } else if (fAny) {
          const int cut = (rlo + fr) - (j0 + fk);     // keep e > cut  (j > i)
          bf16x8 af = a;
#pragma unroll
          for (int e = 0; e < 8; ++e) if (e <= cut) af[e] = (bf16_t)0.f;
#pragma unroll
          for (int t = 0; t < 2; ++t)
            accF[s][t] = __builtin_amdgcn_mfma_f32_16x16x32_bf16(af, bF[t], accF[s][t], 0, 0, 0);
        }
      }
    }
    if (kt + 3 < NT)      { WAIT6(); BAR(); }
    else if (kt + 2 < NT) { WAIT3(); BAR(); }
    else if (kt + 1 < NT) { WAIT0(); BAR(); }
  }
#pragma unroll
  for (int s = 0; s < 2; ++s)
#pragma unroll
    for (int r = 0; r < 4; ++r) {
      const int row = i0 + mw + s * 16 + cr + r;
      const float spv = scaleP[b * SEQ + row];
      const float sfv = scaleF[b * SEQ + row];
#pragma unroll
      for (int t = 0; t < 2; ++t) {
        const int col = blockIdx.x * 64 + nw2 + t * 16 + cc;
        const size_t oi = ((size_t)b * SEQ + row) * HID + col;
        out[oi] = accP[s][t][r] * spv + accF[s][t][r] * sfv + out[oi];  // Gb already in out
      }
    }
}

extern "C" void kernel_launch(void* const* d_in, const int* in_sizes, int n_in,
                              void* d_out, int out_size, void* d_ws, size_t ws_size,
                              hipStream_t stream) {
  const float* F  = (const float*)d_in[0];
  const int*   sm = (const int*)  d_in[1];
  const float* W1 = (const float*)d_in[2];
  const float* b1 = (const float*)d_in[3];
  const float* W2 = (const float*)d_in[4];
  const float* b2 = (const float*)d_in[5];
  float* out = (float*)d_out;

  char* ws = (char*)d_ws;
  size_t off = 0;
  auto take = [&](size_t bytes) -> void* {
    void* p = ws + off;
    off += (bytes + 255) & ~(size_t)255;
    return p;
  };
  bf16_t* Fbf    = (bf16_t*)take((size_t)BATCH * SEQ * DIM * 2);   // 8 MB
  bf16_t* projbf = (bf16_t*)take((size_t)BATCH * SEQ * HID * 2);   // 8 MB
  bf16_t* GacT   = (bf16_t*)take((size_t)BATCH * SEQ * SEQ * 2);   // 16 MB
  bf16_t* Wpg    = (bf16_t*)take((size_t)1024 * 512 * 2);          // 1 MB
  bf16_t* W2ac   = (bf16_t*)take((size_t)1024 * 512 * 2);          // 1 MB
  float*  scaleP = (float*) take((size_t)BATCH * SEQ * 4);
  float*  scaleF = (float*) take((size_t)BATCH * SEQ * 4);

  const size_t wbytes = (size_t)SEQ * SEQ * 2;
  int chunk = (ws_size > off) ? (int)((ws_size - off) / wbytes) : 1;
  if (chunk > BATCH) chunk = BATCH;
  if (chunk < 1) chunk = 1;
  bf16_t* wbuf = (bf16_t*)(ws + off);

  prep_kernel<<<dim3(2568), dim3(256), 0, stream>>>(
      F, sm, W1, W2, Fbf, Wpg, W2ac, scaleP, scaleF);
  pgga_mfma<<<dim3(2048), dim3(256), 0, stream>>>(
      Fbf, Wpg, W2ac, sm, b1, b2, projbf, out, GacT);
  for (int b0 = 0; b0 < BATCH; b0 += chunk) {
    const int nb = (BATCH - b0 < chunk) ? (BATCH - b0) : chunk;
    weight_mfma<<<dim3(SEQ / 64, SEQ / 128, nb), dim3(256), 0, stream>>>(projbf, Fbf, wbuf, b0);
    tri_mfma<<<dim3(HID / 64, SEQ / 64, nb), dim3(256), 0, stream>>>(
        wbuf, GacT, scaleP, scaleF, out, b0);
  }
}

// Round 8
// 121.184 us; speedup vs baseline: 1.0039x; 1.0039x over previous
//
#include <hip/hip_runtime.h>

// PastFutureContext: B=8, N=1024, d=h=512 — bf16 MFMA, ring-4 counted-vmcnt
// (graduated waits, latency tolerance = 2 iters), fused launches (4 total).
// Math: out = sp_i*(trilW @ GaT^T) + sf_i*(triuW @ GcT^T) + Gb, where
//   W[b]    = proj[b] @ F[b]^T        (proj = F@W1^T + b1)
//   GacT[b] = [W2a;W2c] @ F[b]^T * sm_j
//   Gb      = F @ W2b^T + b2   — written straight into out (f32); tri does RMW.
// Launches: prep (scales+cvt+prepw) -> PGGA (pg ∪ gact) -> weight -> tri.
// LDS swizzle (verified r5: conflicts=0): lane l stages global col-slot
// ((l&3)-(l>>3))&3; read slot q(r,c0)=(c0+(r>>1))&3.

constexpr int BATCH = 8;
constexpr int SEQ   = 1024;
constexpr int DIM   = 512;
constexpr int HID   = 512;

typedef __bf16 bf16_t;
typedef bf16_t bf16x8 __attribute__((ext_vector_type(8)));
typedef float  f32x4  __attribute__((ext_vector_type(4)));
typedef float  f4     __attribute__((ext_vector_type(4)));

typedef __attribute__((address_space(1))) void gv_t;
typedef __attribute__((address_space(3))) void lv_t;

__device__ __forceinline__ void gload16(const bf16_t* g, bf16_t* l) {
  __builtin_amdgcn_global_load_lds((gv_t*)g, (lv_t*)l, 16, 0, 0);
}

#define WAIT6() asm volatile("s_waitcnt vmcnt(6)" ::: "memory")
#define WAIT3() asm volatile("s_waitcnt vmcnt(3)" ::: "memory")
#define WAIT0() asm volatile("s_waitcnt vmcnt(0)" ::: "memory")
#define BAR()   { __builtin_amdgcn_s_barrier(); __builtin_amdgcn_sched_barrier(0); }

// Stage a [ROWS x 32] bf16 tile (row-major, ld elems) into LDS as ROWS/16
// chunks of 512 elems. Lane l lands at elem l*8 of its chunk (linear dest).
// Pre-swizzled global source (see header).
template <int ROWS>
__device__ __forceinline__ void stage(const bf16_t* g, int ld, bf16_t* lds,
                                      int w, int lane) {
  const int r0 = lane >> 2;
  const int kc = ((((lane & 3) - (lane >> 3)) & 3)) * 8;
#pragma unroll
  for (int i = 0; i < ROWS / 64; ++i) {
    const int s = w * (ROWS / 64) + i;
    gload16(g + (size_t)(s * 16 + r0) * ld + kc, lds + s * 512);
  }
}

// read-side swizzled elem offset within a 16-row chunk (row fr, global slot c0)
__device__ __forceinline__ int swz8(int fr, int c0) {
  return (((fr << 2) | ((c0 + (fr >> 1)) & 3)) << 3);
}

// ---- fused prep: cvt F (blocks 0..2047) | prepw (2048..2559) | scales (2560..2567)
__global__ __launch_bounds__(256) void prep_kernel(
    const float* __restrict__ F, const int* __restrict__ smask,
    const float* __restrict__ W1, const float* __restrict__ W2,
    bf16_t* __restrict__ Fbf, bf16_t* __restrict__ Wpg, bf16_t* __restrict__ W2ac,
    float* __restrict__ sp, float* __restrict__ sf) {
  const int bid = blockIdx.x, tid = threadIdx.x;
  if (bid < 2048) {                       // cvt: 8 f32 -> bf16 per thread
    const int i = bid * 256 + tid;        // i < 524288
    const f4* p = (const f4*)(F + (size_t)i * 8);
    f4 v0 = p[0], v1 = p[1];
    bf16x8 o;
    o[0] = (bf16_t)v0[0]; o[1] = (bf16_t)v0[1]; o[2] = (bf16_t)v0[2]; o[3] = (bf16_t)v0[3];
    o[4] = (bf16_t)v1[0]; o[5] = (bf16_t)v1[1]; o[6] = (bf16_t)v1[2]; o[7] = (bf16_t)v1[3];
    *(bf16x8*)(Fbf + (size_t)i * 8) = o;
    return;
  }
  if (bid < 2560) {                       // prepw: restack W1/W2 -> Wpg, W2ac
    const int idx = (bid - 2048) * 256 + tid;
    const int r = idx >> 6, c8 = (idx & 63) * 8;
    const float* src;
    bf16_t* dst;
    if (r < 512)       { src = W1 + (size_t)r * 512 + c8;                  dst = Wpg  + (size_t)r * 512 + c8; }
    else if (r < 1024) { src = W2 + (size_t)(r - 512) * 1536 + 512 + c8;   dst = Wpg  + (size_t)r * 512 + c8; }
    else if (r < 1536) { src = W2 + (size_t)(r - 1024) * 1536 + c8;        dst = W2ac + (size_t)(r - 1024) * 512 + c8; }
    else               { src = W2 + (size_t)(r - 1536) * 1536 + 1024 + c8; dst = W2ac + (size_t)(r - 1024) * 512 + c8; }
    f4 v0 = *(const f4*)src, v1 = *(const f4*)(src + 4);
    bf16x8 o;
    o[0] = (bf16_t)v0[0]; o[1] = (bf16_t)v0[1]; o[2] = (bf16_t)v0[2]; o[3] = (bf16_t)v0[3];
    o[4] = (bf16_t)v1[0]; o[5] = (bf16_t)v1[1]; o[6] = (bf16_t)v1[2]; o[7] = (bf16_t)v1[3];
    *(bf16x8*)dst = o;
    return;
  }
  // scales: batch = bid - 2560; 256 thr x 4 elems, wave scan + block combine
  const int b = bid - 2560;
  const int4 v4 = ((const int4*)(smask + b * SEQ))[tid];
  const int tsum = v4.x + v4.y + v4.z + v4.w;
  int x = tsum;
#pragma unroll
  for (int o = 1; o < 64; o <<= 1) {
    int y = __shfl_up(x, o, 64);
    if ((tid & 63) >= o) x += y;
  }
  __shared__ int wsum[4], wpre[5];
  if ((tid & 63) == 63) wsum[tid >> 6] = x;
  __syncthreads();
  if (tid == 0) { int c = 0; for (int w = 0; w < 4; ++w) { wpre[w] = c; c += wsum[w]; } wpre[4] = c; }
  __syncthreads();
  const int excl = (x - tsum) + wpre[tid >> 6];   // elems before this thread's 4
  const float tot = (float)wpre[4];
  f4 spv, sfv;
  int pre = excl;
  const int e[4] = {v4.x, v4.y, v4.z, v4.w};
#pragma unroll
  for (int i = 0; i < 4; ++i) {
    const float P  = (float)pre;
    const float Fu = tot - (float)pre - (float)e[i];
    spv[i] = e[i] ? 1.f / (P  + 1e-8f) : 0.f;
    sfv[i] = e[i] ? 1.f / (Fu + 1e-8f) : 0.f;
    pre += e[i];
  }
  ((f4*)(sp + b * SEQ))[tid] = spv;
  ((f4*)(sf + b * SEQ))[tid] = sfv;
}

// ---- ring-4 counted-vmcnt 128x64 GEMM core (wave 64x32, acc 4x2) -------------
// 3 loads/iter/thread; prologue 3 tiles (9 loads); wait vmcnt(6) = oldest tile
// landed, 2 tiles in flight across the barrier. Graduated epilogue 6/3/0.
__device__ __forceinline__ void gemm_ring(
    const bf16_t* __restrict__ A, int lda, const bf16_t* __restrict__ Bt, int ldb,
    int K, bf16_t* As, bf16_t* Bs, f32x4 acc[4][2],
    int w, int lane, int qoff, int mw, int nw) {
  const int NT = K / 32;
#pragma unroll
  for (int p = 0; p < 3; ++p) {
    stage<128>(A + p * 32, lda, As + p * 4096, w, lane);
    stage<64>(Bt + p * 32, ldb, Bs + p * 2048, w, lane);
  }
  WAIT6();
  BAR();
  for (int k = 0; k < NT; ++k) {
    const int cur = k & 3;
    if (k + 3 < NT) {
      const int nx = (k + 3) & 3;
      stage<128>(A  + (k + 3) * 32, lda, As + nx * 4096, w, lane);
      stage<64>(Bt + (k + 3) * 32, ldb, Bs + nx * 2048, w, lane);
    }
    const bf16_t* ab = As + cur * 4096 + (mw >> 4) * 512 + qoff;
    const bf16_t* bb = Bs + cur * 2048 + (nw >> 4) * 512 + qoff;
    bf16x8 a[4], b[2];
#pragma unroll
    for (int s = 0; s < 4; ++s) a[s] = *(const bf16x8*)&ab[s * 512];
#pragma unroll
    for (int t = 0; t < 2; ++t) b[t] = *(const bf16x8*)&bb[t * 512];
#pragma unroll
    for (int s = 0; s < 4; ++s)
#pragma unroll
      for (int t = 0; t < 2; ++t)
        acc[s][t] = __builtin_amdgcn_mfma_f32_16x16x32_bf16(a[s], b[t], acc[s][t], 0, 0, 0);
    if (k + 3 < NT)      { WAIT6(); BAR(); }
    else if (k + 2 < NT) { WAIT3(); BAR(); }
    else if (k + 1 < NT) { WAIT0(); BAR(); }
  }
}

// ---- PGGA: union grid — blocks [0,1024): pg; [1024,2048): gact ---------------
__global__ __launch_bounds__(256) void pgga_mfma(
    const bf16_t* __restrict__ Fbf, const bf16_t* __restrict__ Wpg,
    const bf16_t* __restrict__ W2ac, const int* __restrict__ smask,
    const float* __restrict__ b1, const float* __restrict__ b2,
    bf16_t* __restrict__ projbf, float* __restrict__ out,
    bf16_t* __restrict__ GacT) {
  __shared__ bf16_t As[4 * 4096], Bs[4 * 2048];
  const int tid = threadIdx.x;
  const int w = tid >> 6, lane = tid & 63;
  const int fr = lane & 15;
  const int qoff = swz8(fr, lane >> 4);
  const int mw = (w >> 1) * 64, nw = (w & 1) * 32;
  const int cr = (lane >> 4) * 4, cc = lane & 15;
  const int bid = blockIdx.x;
  f32x4 acc[4][2] = {};
  if (bid < 1024) {
    // pg: [proj | Gb] = F @ [W1;W2b]^T + [b1;b2]
    const int m0 = (bid >> 4) * 128, n0 = (bid & 15) * 64;
    gemm_ring(Fbf + (size_t)m0 * DIM, DIM, Wpg + (size_t)n0 * DIM, DIM, DIM,
              As, Bs, acc, w, lane, qoff, mw, nw);
    if (n0 < 512) {
#pragma unroll
      for (int s = 0; s < 4; ++s)
#pragma unroll
        for (int t = 0; t < 2; ++t) {
          const int col = n0 + nw + t * 16 + cc;
          const float bv = b1[col];
#pragma unroll
          for (int r = 0; r < 4; ++r)
            projbf[(size_t)(m0 + mw + s * 16 + cr + r) * HID + col] = (bf16_t)(acc[s][t][r] + bv);
        }
    } else {
#pragma unroll
      for (int s = 0; s < 4; ++s)
#pragma unroll
        for (int t = 0; t < 2; ++t) {
          const int col = (n0 - 512) + nw + t * 16 + cc;
          const float bv = b2[col];
#pragma unroll
          for (int r = 0; r < 4; ++r)
            out[(size_t)(m0 + mw + s * 16 + cr + r) * HID + col] = acc[s][t][r] + bv;
        }
    }
  } else {
    // gact: GacT[b][m][j] = ([W2a;W2c] @ F[b]^T)[m][j] * sm_j
    const int q = bid - 1024;
    const int b = q >> 7, r7 = q & 127;
    const int m0 = (r7 >> 4) * 128, n0 = (r7 & 15) * 64;
    const bf16_t* Bt = Fbf + (size_t)b * SEQ * DIM;
    gemm_ring(W2ac + (size_t)m0 * DIM, DIM, Bt + (size_t)n0 * DIM, DIM, DIM,
              As, Bs, acc, w, lane, qoff, mw, nw);
    bf16_t* C = GacT + (size_t)b * SEQ * SEQ;
#pragma unroll
    for (int s = 0; s < 4; ++s)
#pragma unroll
      for (int t = 0; t < 2; ++t) {
        const int j = n0 + nw + t * 16 + cc;
        const float smj = (float)smask[b * SEQ + j];
#pragma unroll
        for (int r = 0; r < 4; ++r)
          C[(size_t)(m0 + mw + s * 16 + cr + r) * SEQ + j] = (bf16_t)(acc[s][t][r] * smj);
      }
  }
}

// ---- weight[b] = proj[b] @ F[b]^T ---------------------------------------------
__global__ __launch_bounds__(256) void weight_mfma(
    const bf16_t* __restrict__ projbf, const bf16_t* __restrict__ Fbf,
    bf16_t* __restrict__ wbuf, int b0) {
  __shared__ bf16_t As[4 * 4096], Bs[4 * 2048];
  const int tid = threadIdx.x;
  const int w = tid >> 6, lane = tid & 63;
  const int fr = lane & 15;
  const int qoff = swz8(fr, lane >> 4);
  const int mw = (w >> 1) * 64, nw = (w & 1) * 32;
  const int cr = (lane >> 4) * 4, cc = lane & 15;
  const int b = b0 + blockIdx.z;
  const bf16_t* A  = projbf + (size_t)b * SEQ * DIM;
  const bf16_t* Bt = Fbf    + (size_t)b * SEQ * DIM;
  bf16_t* C = wbuf + (size_t)blockIdx.z * SEQ * SEQ;
  const int m0 = blockIdx.y * 128, n0 = blockIdx.x * 64;
  f32x4 acc[4][2] = {};
  gemm_ring(A + (size_t)m0 * DIM, DIM, Bt + (size_t)n0 * DIM, DIM, DIM,
            As, Bs, acc, w, lane, qoff, mw, nw);
#pragma unroll
  for (int s = 0; s < 4; ++s)
#pragma unroll
    for (int t = 0; t < 2; ++t)
#pragma unroll
      for (int r = 0; r < 4; ++r)
        C[(size_t)(m0 + mw + s * 16 + cr + r) * SEQ + n0 + nw + t * 16 + cc] = (bf16_t)acc[s][t][r];
}

// ---- tri — out += sp*(trilW @ GaT^T) + sf*(triuW @ GcT^T) ---------------------
// block 64(i) x 64(n); waves 2x2 (32x32); ring-4, 3 loads/iter.
__global__ __launch_bounds__(256) void tri_mfma(
    const bf16_t* __restrict__ wbuf, const bf16_t* __restrict__ GacT,
    const float* __restrict__ scaleP, const float* __restrict__ scaleF,
    float* __restrict__ out, int b0) {
  __shared__ bf16_t As[4 * 2048], BPs[4 * 2048], BFs[4 * 2048];
  const int tid = threadIdx.x;
  const int w = tid >> 6, lane = tid & 63;
  const int fr = lane & 15, fk = (lane >> 4) * 8;
  const int qoff = swz8(fr, lane >> 4);
  const int mw = (w >> 1) * 32, nw2 = (w & 1) * 32;
  const int cr = (lane >> 4) * 4, cc = lane & 15;
  const int b = b0 + blockIdx.z;
  const bf16_t* A    = wbuf + (size_t)blockIdx.z * SEQ * SEQ;
  const bf16_t* GaTp = GacT + (size_t)b * SEQ * SEQ + (size_t)(blockIdx.x * 64) * SEQ;
  const bf16_t* GaTf = GaTp + (size_t)512 * SEQ;
  const int i0 = blockIdx.y * 64;
  f32x4 accP[2][2] = {}, accF[2][2] = {};
  const bf16_t* Arow = A + (size_t)i0 * SEQ;
#pragma unroll
  for (int p = 0; p < 3; ++p) {
    stage<64>(Arow + p * 32, SEQ, As  + p * 2048, w, lane);
    stage<64>(GaTp + p * 32, SEQ, BPs + p * 2048, w, lane);
    stage<64>(GaTf + p * 32, SEQ, BFs + p * 2048, w, lane);
  }
  WAIT6();
  BAR();
  const int NT = SEQ / 32;
  for (int kt = 0; kt < NT; ++kt) {
    const int j0 = kt * 32;
    const int cur = kt & 3;
    if (kt + 3 < NT) {
      const int nx = (kt + 3) & 3;
      const int jn = j0 + 96;
      stage<64>(Arow + jn, SEQ, As  + nx * 2048, w, lane);
      stage<64>(GaTp + jn, SEQ, BPs + nx * 2048, w, lane);
      stage<64>(GaTf + jn, SEQ, BFs + nx * 2048, w, lane);
    }
    const bool wP = (j0 < i0 + mw + 31);      // any s has pAny
    const bool wF = (j0 + 31 > i0 + mw);      // any s has fAny
    if (wP || wF) {
      const bf16_t* abase  = As  + cur * 2048 + (mw >> 4) * 512 + qoff;
      const bf16_t* bpbase = BPs + cur * 2048 + (nw2 >> 4) * 512 + qoff;
      const bf16_t* bfbase = BFs + cur * 2048 + (nw2 >> 4) * 512 + qoff;
      bf16x8 bP[2], bF[2];
#pragma unroll
      for (int t = 0; t < 2; ++t) {
        if (wP) bP[t] = *(const bf16x8*)&bpbase[t * 512];
        if (wF) bF[t] = *(const bf16x8*)&bfbase[t * 512];
      }
#pragma unroll
      for (int s = 0; s < 2; ++s) {
        const int rlo = i0 + mw + s * 16;
        const bool pAny = (j0 < rlo + 15), pFull = (j0 + 31 < rlo);
        const bool fAny = (j0 + 31 > rlo), fFull = (j0 > rlo + 15);
        if (!pAny && !fAny) continue;
        const bf16x8 a = *(const bf16x8*)&abase[s * 512];
        if (pFull) {
#pragma unroll
          for (int t = 0; t < 2; ++t)
            accP[s][t] = __builtin_amdgcn_mfma_f32_16x16x32_bf16(a, bP[t], accP[s][t], 0, 0, 0);
        } else if (pAny) {
          const int cut = (rlo + fr) - (j0 + fk);     // keep e < cut  (j < i)
          bf16x8 ap = a;
#pragma unroll
          for (int e = 0; e < 8; ++e) if (e >= cut) ap[e] = (bf16_t)0.f;
#pragma unroll
          for (int t = 0; t < 2; ++t)
            accP[s][t] = __builtin_amdgcn_mfma_f32_16x16x32_bf16(ap, bP[t], accP[s][t], 0, 0, 0);
        }
        if (fFull) {
#pragma unroll
          for (int t = 0; t < 2; ++t)
            accF[s][t] = __builtin_amdgcn_mfma_f32_16x16x32_bf16(a, bF[t], accF[s][t], 0, 0, 0);
        } else if (fAny) {
          const int cut = (rlo + fr) - (j0 + fk);     // keep e > cut  (j > i)
          bf16x8 af = a;
#pragma unroll
          for (int e = 0; e < 8; ++e) if (e <= cut) af[e] = (bf16_t)0.f;
#pragma unroll
          for (int t = 0; t < 2; ++t)
            accF[s][t] = __builtin_amdgcn_mfma_f32_16x16x32_bf16(af, bF[t], accF[s][t], 0, 0, 0);
        }
      }
    }
    if (kt + 3 < NT)      { WAIT6(); BAR(); }
    else if (kt + 2 < NT) { WAIT3(); BAR(); }
    else if (kt + 1 < NT) { WAIT0(); BAR(); }
  }
#pragma unroll
  for (int s = 0; s < 2; ++s)
#pragma unroll
    for (int r = 0; r < 4; ++r) {
      const int row = i0 + mw + s * 16 + cr + r;
      const float spv = scaleP[b * SEQ + row];
      const float sfv = scaleF[b * SEQ + row];
#pragma unroll
      for (int t = 0; t < 2; ++t) {
        const int col = blockIdx.x * 64 + nw2 + t * 16 + cc;
        const size_t oi = ((size_t)b * SEQ + row) * HID + col;
        out[oi] = accP[s][t][r] * spv + accF[s][t][r] * sfv + out[oi];  // Gb already in out
      }
    }
}

extern "C" void kernel_launch(void* const* d_in, const int* in_sizes, int n_in,
                              void* d_out, int out_size, void* d_ws, size_t ws_size,
                              hipStream_t stream) {
  const float* F  = (const float*)d_in[0];
  const int*   sm = (const int*)  d_in[1];
  const float* W1 = (const float*)d_in[2];
  const float* b1 = (const float*)d_in[3];
  const float* W2 = (const float*)d_in[4];
  const float* b2 = (const float*)d_in[5];
  float* out = (float*)d_out;

  char* ws = (char*)d_ws;
  size_t off = 0;
  auto take = [&](size_t bytes) -> void* {
    void* p = ws + off;
    off += (bytes + 255) & ~(size_t)255;
    return p;
  };
  bf16_t* Fbf    = (bf16_t*)take((size_t)BATCH * SEQ * DIM * 2);   // 8 MB
  bf16_t* projbf = (bf16_t*)take((size_t)BATCH * SEQ * HID * 2);   // 8 MB
  bf16_t* GacT   = (bf16_t*)take((size_t)BATCH * SEQ * SEQ * 2);   // 16 MB
  bf16_t* Wpg    = (bf16_t*)take((size_t)1024 * 512 * 2);          // 1 MB
  bf16_t* W2ac   = (bf16_t*)take((size_t)1024 * 512 * 2);          // 1 MB
  float*  scaleP = (float*) take((size_t)BATCH * SEQ * 4);
  float*  scaleF = (float*) take((size_t)BATCH * SEQ * 4);

  const size_t wbytes = (size_t)SEQ * SEQ * 2;
  int chunk = (ws_size > off) ? (int)((ws_size - off) / wbytes) : 1;
  if (chunk > BATCH) chunk = BATCH;
  if (chunk < 1) chunk = 1;
  bf16_t* wbuf = (bf16_t*)(ws + off);

  prep_kernel<<<dim3(2568), dim3(256), 0, stream>>>(
      F, sm, W1, W2, Fbf, Wpg, W2ac, scaleP, scaleF);
  pgga_mfma<<<dim3(2048), dim3(256), 0, stream>>>(
      Fbf, Wpg, W2ac, sm, b1, b2, projbf, out, GacT);
  for (int b0 = 0; b0 < BATCH; b0 += chunk) {
    const int nb = (BATCH - b0 < chunk) ? (BATCH - b0) : chunk;
    weight_mfma<<<dim3(SEQ / 64, SEQ / 128, nb), dim3(256), 0, stream>>>(projbf, Fbf, wbuf, b0);
    tri_mfma<<<dim3(HID / 64, SEQ / 64, nb), dim3(256), 0, stream>>>(
        wbuf, GacT, scaleP, scaleF, out, b0);
  }
}

// Round 9
// 116.316 us; speedup vs baseline: 1.0459x; 1.0418x over previous
//
#include <hip/hip_runtime.h>

// PastFutureContext: B=8, N=1024, d=h=512 — bf16 MFMA.
// Round 9: BK=64 sync intervals (16 MFMA/wave/interval), dbuf-2, catalog 2-phase
// { STAGE(k+1) ; compute(k) ; vmcnt(0)+barrier }. Halves interval count vs r6.
// Math: out = sp_i*(trilW @ GaT^T) + sf_i*(triuW @ GcT^T) + Gb, where
//   W[b]    = proj[b] @ F[b]^T        (proj = F@W1^T + b1)
//   GacT[b] = [W2a;W2c] @ F[b]^T * sm_j
//   Gb      = F @ W2b^T + b2   — written straight into out (f32); tri does RMW.
// LDS swizzle (verified r5: conflicts=0): lane l stages global col-slot
// ((l&3)-(l>>3))&3; read slot q(r,c0)=(c0+(r>>1))&3.

constexpr int BATCH = 8;
constexpr int SEQ   = 1024;
constexpr int DIM   = 512;
constexpr int HID   = 512;

typedef __bf16 bf16_t;
typedef bf16_t bf16x8 __attribute__((ext_vector_type(8)));
typedef float  f32x4  __attribute__((ext_vector_type(4)));
typedef float  f4     __attribute__((ext_vector_type(4)));

typedef __attribute__((address_space(1))) void gv_t;
typedef __attribute__((address_space(3))) void lv_t;

__device__ __forceinline__ void gload16(const bf16_t* g, bf16_t* l) {
  __builtin_amdgcn_global_load_lds((gv_t*)g, (lv_t*)l, 16, 0, 0);
}

#define WAIT0() asm volatile("s_waitcnt vmcnt(0)" ::: "memory")
#define BAR()   { __builtin_amdgcn_s_barrier(); __builtin_amdgcn_sched_barrier(0); }

// Stage a [ROWS x 32] bf16 subtile (row-major, ld elems) into LDS as ROWS/16
// chunks of 512 elems; linear dest, pre-swizzled global source (see header).
template <int ROWS>
__device__ __forceinline__ void stage(const bf16_t* g, int ld, bf16_t* lds,
                                      int w, int lane) {
  const int r0 = lane >> 2;
  const int kc = ((((lane & 3) - (lane >> 3)) & 3)) * 8;
#pragma unroll
  for (int i = 0; i < ROWS / 64; ++i) {
    const int s = w * (ROWS / 64) + i;
    gload16(g + (size_t)(s * 16 + r0) * ld + kc, lds + s * 512);
  }
}

// Stage a [ROWS x 64] tile as two 32-col subtiles (subtile c at +c*ROWS*32).
template <int ROWS>
__device__ __forceinline__ void stage64(const bf16_t* g, int ld, bf16_t* lds,
                                        int w, int lane) {
  stage<ROWS>(g, ld, lds, w, lane);
  stage<ROWS>(g + 32, ld, lds + ROWS * 32, w, lane);
}

// read-side swizzled elem offset within a 16-row chunk (row fr, global slot c0)
__device__ __forceinline__ int swz8(int fr, int c0) {
  return (((fr << 2) | ((c0 + (fr >> 1)) & 3)) << 3);
}

// ---- fused prep: cvt F (blocks 0..2047) | prepw (2048..2559) | scales (2560..2567)
__global__ __launch_bounds__(256) void prep_kernel(
    const float* __restrict__ F, const int* __restrict__ smask,
    const float* __restrict__ W1, const float* __restrict__ W2,
    bf16_t* __restrict__ Fbf, bf16_t* __restrict__ Wpg, bf16_t* __restrict__ W2ac,
    float* __restrict__ sp, float* __restrict__ sf) {
  const int bid = blockIdx.x, tid = threadIdx.x;
  if (bid < 2048) {                       // cvt: 8 f32 -> bf16 per thread
    const int i = bid * 256 + tid;
    const f4* p = (const f4*)(F + (size_t)i * 8);
    f4 v0 = p[0], v1 = p[1];
    bf16x8 o;
    o[0] = (bf16_t)v0[0]; o[1] = (bf16_t)v0[1]; o[2] = (bf16_t)v0[2]; o[3] = (bf16_t)v0[3];
    o[4] = (bf16_t)v1[0]; o[5] = (bf16_t)v1[1]; o[6] = (bf16_t)v1[2]; o[7] = (bf16_t)v1[3];
    *(bf16x8*)(Fbf + (size_t)i * 8) = o;
    return;
  }
  if (bid < 2560) {                       // prepw: restack W1/W2 -> Wpg, W2ac
    const int idx = (bid - 2048) * 256 + tid;
    const int r = idx >> 6, c8 = (idx & 63) * 8;
    const float* src;
    bf16_t* dst;
    if (r < 512)       { src = W1 + (size_t)r * 512 + c8;                  dst = Wpg  + (size_t)r * 512 + c8; }
    else if (r < 1024) { src = W2 + (size_t)(r - 512) * 1536 + 512 + c8;   dst = Wpg  + (size_t)r * 512 + c8; }
    else if (r < 1536) { src = W2 + (size_t)(r - 1024) * 1536 + c8;        dst = W2ac + (size_t)(r - 1024) * 512 + c8; }
    else               { src = W2 + (size_t)(r - 1536) * 1536 + 1024 + c8; dst = W2ac + (size_t)(r - 1024) * 512 + c8; }
    f4 v0 = *(const f4*)src, v1 = *(const f4*)(src + 4);
    bf16x8 o;
    o[0] = (bf16_t)v0[0]; o[1] = (bf16_t)v0[1]; o[2] = (bf16_t)v0[2]; o[3] = (bf16_t)v0[3];
    o[4] = (bf16_t)v1[0]; o[5] = (bf16_t)v1[1]; o[6] = (bf16_t)v1[2]; o[7] = (bf16_t)v1[3];
    *(bf16x8*)dst = o;
    return;
  }
  // scales: batch = bid - 2560; 256 thr x 4 elems, wave scan + block combine
  const int b = bid - 2560;
  const int4 v4 = ((const int4*)(smask + b * SEQ))[tid];
  const int tsum = v4.x + v4.y + v4.z + v4.w;
  int x = tsum;
#pragma unroll
  for (int o = 1; o < 64; o <<= 1) {
    int y = __shfl_up(x, o, 64);
    if ((tid & 63) >= o) x += y;
  }
  __shared__ int wsum[4], wpre[5];
  if ((tid & 63) == 63) wsum[tid >> 6] = x;
  __syncthreads();
  if (tid == 0) { int c = 0; for (int w = 0; w < 4; ++w) { wpre[w] = c; c += wsum[w]; } wpre[4] = c; }
  __syncthreads();
  const int excl = (x - tsum) + wpre[tid >> 6];
  const float tot = (float)wpre[4];
  f4 spv, sfv;
  int pre = excl;
  const int e[4] = {v4.x, v4.y, v4.z, v4.w};
#pragma unroll
  for (int i = 0; i < 4; ++i) {
    const float P  = (float)pre;
    const float Fu = tot - (float)pre - (float)e[i];
    spv[i] = e[i] ? 1.f / (P  + 1e-8f) : 0.f;
    sfv[i] = e[i] ? 1.f / (Fu + 1e-8f) : 0.f;
    pre += e[i];
  }
  ((f4*)(sp + b * SEQ))[tid] = spv;
  ((f4*)(sf + b * SEQ))[tid] = sfv;
}

// ---- BK=64 dbuf-2 GEMM core: tile 128(m) x 64(n), 16 MFMA/wave/interval ------
// As buf: 128x64 = 8192 elems (2 subtiles of 4096); Bs buf: 64x64 = 4096 (2x2048).
__device__ __forceinline__ void gemm_db64(
    const bf16_t* __restrict__ A, int lda, const bf16_t* __restrict__ Bt, int ldb,
    int K, bf16_t* As, bf16_t* Bs, f32x4 acc[4][2],
    int w, int lane, int qoff, int mw, int nw) {
  const int NT = K / 64;
  stage64<128>(A, lda, As, w, lane);
  stage64<64>(Bt, ldb, Bs, w, lane);
  WAIT0(); BAR();
  for (int k = 0; k < NT; ++k) {
    const int cur = k & 1;
    if (k + 1 < NT) {
      stage64<128>(A  + (k + 1) * 64, lda, As + (cur ^ 1) * 8192, w, lane);
      stage64<64>(Bt + (k + 1) * 64, ldb, Bs + (cur ^ 1) * 4096, w, lane);
    }
#pragma unroll
    for (int ks = 0; ks < 2; ++ks) {
      const bf16_t* ab = As + cur * 8192 + ks * 4096 + (mw >> 4) * 512 + qoff;
      const bf16_t* bb = Bs + cur * 4096 + ks * 2048 + (nw >> 4) * 512 + qoff;
      bf16x8 a[4], b[2];
#pragma unroll
      for (int s = 0; s < 4; ++s) a[s] = *(const bf16x8*)&ab[s * 512];
#pragma unroll
      for (int t = 0; t < 2; ++t) b[t] = *(const bf16x8*)&bb[t * 512];
#pragma unroll
      for (int s = 0; s < 4; ++s)
#pragma unroll
        for (int t = 0; t < 2; ++t)
          acc[s][t] = __builtin_amdgcn_mfma_f32_16x16x32_bf16(a[s], b[t], acc[s][t], 0, 0, 0);
    }
    WAIT0(); BAR();
  }
}

#define TILE_IDS                                  \
  const int tid = threadIdx.x;                    \
  const int w = tid >> 6, lane = tid & 63;        \
  const int fr = lane & 15;                       \
  const int qoff = swz8(fr, lane >> 4);           \
  const int mw = (w >> 1) * 64, nw = (w & 1) * 32;\
  const int cr = (lane >> 4) * 4, cc = lane & 15;

// ---- pg: [proj | Gb] = F @ [W1;W2b]^T + [b1;b2]; Gb straight into out --------
__global__ __launch_bounds__(256) void pg_mfma(
    const bf16_t* __restrict__ Fbf, const bf16_t* __restrict__ Wpg,
    const float* __restrict__ b1, const float* __restrict__ b2,
    bf16_t* __restrict__ projbf, float* __restrict__ out) {
  __shared__ bf16_t As[2 * 8192], Bs[2 * 4096];
  TILE_IDS
  const int m0 = blockIdx.y * 128, n0 = blockIdx.x * 64;
  f32x4 acc[4][2] = {};
  gemm_db64(Fbf + (size_t)m0 * DIM, DIM, Wpg + (size_t)n0 * DIM, DIM, DIM,
            As, Bs, acc, w, lane, qoff, mw, nw);
  if (n0 < 512) {
#pragma unroll
    for (int s = 0; s < 4; ++s)
#pragma unroll
      for (int t = 0; t < 2; ++t) {
        const int col = n0 + nw + t * 16 + cc;
        const float bv = b1[col];
#pragma unroll
        for (int r = 0; r < 4; ++r)
          projbf[(size_t)(m0 + mw + s * 16 + cr + r) * HID + col] = (bf16_t)(acc[s][t][r] + bv);
      }
  } else {
#pragma unroll
    for (int s = 0; s < 4; ++s)
#pragma unroll
      for (int t = 0; t < 2; ++t) {
        const int col = (n0 - 512) + nw + t * 16 + cc;
        const float bv = b2[col];
#pragma unroll
        for (int r = 0; r < 4; ++r)
          out[(size_t)(m0 + mw + s * 16 + cr + r) * HID + col] = acc[s][t][r] + bv;
      }
  }
}

// ---- gact: GacT[b][m][j] = ([W2a;W2c] @ F[b]^T)[m][j] * sm_j ------------------
__global__ __launch_bounds__(256) void gact_mfma(
    const bf16_t* __restrict__ W2ac, const bf16_t* __restrict__ Fbf,
    const int* __restrict__ smask, bf16_t* __restrict__ GacT) {
  __shared__ bf16_t As[2 * 8192], Bs[2 * 4096];
  TILE_IDS
  const int b = blockIdx.z;
  const bf16_t* Bt = Fbf + (size_t)b * SEQ * DIM;
  const int m0 = blockIdx.y * 128, n0 = blockIdx.x * 64;
  f32x4 acc[4][2] = {};
  gemm_db64(W2ac + (size_t)m0 * DIM, DIM, Bt + (size_t)n0 * DIM, DIM, DIM,
            As, Bs, acc, w, lane, qoff, mw, nw);
  bf16_t* C = GacT + (size_t)b * SEQ * SEQ;
#pragma unroll
  for (int s = 0; s < 4; ++s)
#pragma unroll
    for (int t = 0; t < 2; ++t) {
      const int j = n0 + nw + t * 16 + cc;
      const float smj = (float)smask[b * SEQ + j];
#pragma unroll
      for (int r = 0; r < 4; ++r)
        C[(size_t)(m0 + mw + s * 16 + cr + r) * SEQ + j] = (bf16_t)(acc[s][t][r] * smj);
    }
}

// ---- weight[b] = proj[b] @ F[b]^T ---------------------------------------------
__global__ __launch_bounds__(256) void weight_mfma(
    const bf16_t* __restrict__ projbf, const bf16_t* __restrict__ Fbf,
    bf16_t* __restrict__ wbuf, int b0) {
  __shared__ bf16_t As[2 * 8192], Bs[2 * 4096];
  TILE_IDS
  const int b = b0 + blockIdx.z;
  const bf16_t* A  = projbf + (size_t)b * SEQ * DIM;
  const bf16_t* Bt = Fbf    + (size_t)b * SEQ * DIM;
  bf16_t* C = wbuf + (size_t)blockIdx.z * SEQ * SEQ;
  const int m0 = blockIdx.y * 128, n0 = blockIdx.x * 64;
  f32x4 acc[4][2] = {};
  gemm_db64(A + (size_t)m0 * DIM, DIM, Bt + (size_t)n0 * DIM, DIM, DIM,
            As, Bs, acc, w, lane, qoff, mw, nw);
#pragma unroll
  for (int s = 0; s < 4; ++s)
#pragma unroll
    for (int t = 0; t < 2; ++t)
#pragma unroll
      for (int r = 0; r < 4; ++r)
        C[(size_t)(m0 + mw + s * 16 + cr + r) * SEQ + n0 + nw + t * 16 + cc] = (bf16_t)acc[s][t][r];
}

// ---- tri — out += sp*(trilW @ GaT^T) + sf*(triuW @ GcT^T) ---------------------
// block 64(i) x 64(n); waves 2x2 (32x32); BK=64 dbuf-2, 16 intervals.
__global__ __launch_bounds__(256) void tri_mfma(
    const bf16_t* __restrict__ wbuf, const bf16_t* __restrict__ GacT,
    const float* __restrict__ scaleP, const float* __restrict__ scaleF,
    float* __restrict__ out, int b0) {
  __shared__ bf16_t As[2 * 4096], BPs[2 * 4096], BFs[2 * 4096];   // 64x64 each buf
  const int tid = threadIdx.x;
  const int w = tid >> 6, lane = tid & 63;
  const int fr = lane & 15, fk = (lane >> 4) * 8;
  const int qoff = swz8(fr, lane >> 4);
  const int mw = (w >> 1) * 32, nw2 = (w & 1) * 32;
  const int cr = (lane >> 4) * 4, cc = lane & 15;
  const int b = b0 + blockIdx.z;
  const bf16_t* A    = wbuf + (size_t)blockIdx.z * SEQ * SEQ;
  const bf16_t* GaTp = GacT + (size_t)b * SEQ * SEQ + (size_t)(blockIdx.x * 64) * SEQ;
  const bf16_t* GaTf = GaTp + (size_t)512 * SEQ;
  const int i0 = blockIdx.y * 64;
  f32x4 accP[2][2] = {}, accF[2][2] = {};
  const bf16_t* Arow = A + (size_t)i0 * SEQ;
  stage64<64>(Arow, SEQ, As,  w, lane);
  stage64<64>(GaTp, SEQ, BPs, w, lane);
  stage64<64>(GaTf, SEQ, BFs, w, lane);
  WAIT0(); BAR();
  const int NT = SEQ / 64;
  for (int kt = 0; kt < NT; ++kt) {
    const int cur = kt & 1;
    if (kt + 1 < NT) {
      const int jn = (kt + 1) * 64;
      stage64<64>(Arow + jn, SEQ, As  + (cur ^ 1) * 4096, w, lane);
      stage64<64>(GaTp + jn, SEQ, BPs + (cur ^ 1) * 4096, w, lane);
      stage64<64>(GaTf + jn, SEQ, BFs + (cur ^ 1) * 4096, w, lane);
    }
#pragma unroll
    for (int ks = 0; ks < 2; ++ks) {
      const int j0 = kt * 64 + ks * 32;
      const bool wP = (j0 < i0 + mw + 31);      // any s has pAny
      const bool wF = (j0 + 31 > i0 + mw);      // any s has fAny
      if (!wP && !wF) continue;
      const bf16_t* abase  = As  + cur * 4096 + ks * 2048 + (mw >> 4) * 512 + qoff;
      const bf16_t* bpbase = BPs + cur * 4096 + ks * 2048 + (nw2 >> 4) * 512 + qoff;
      const bf16_t* bfbase = BFs + cur * 4096 + ks * 2048 + (nw2 >> 4) * 512 + qoff;
      bf16x8 bP[2], bF[2];
#pragma unroll
      for (int t = 0; t < 2; ++t) {
        if (wP) bP[t] = *(const bf16x8*)&bpbase[t * 512];
        if (wF) bF[t] = *(const bf16x8*)&bfbase[t * 512];
      }
#pragma unroll
      for (int s = 0; s < 2; ++s) {
        const int rlo = i0 + mw + s * 16;
        const bool pAny = (j0 < rlo + 15), pFull = (j0 + 31 < rlo);
        const bool fAny = (j0 + 31 > rlo), fFull = (j0 > rlo + 15);
        if (!pAny && !fAny) continue;
        const bf16x8 a = *(const bf16x8*)&abase[s * 512];
        if (pFull) {
#pragma unroll
          for (int t = 0; t < 2; ++t)
            accP[s][t] = __builtin_amdgcn_mfma_f32_16x16x32_bf16(a, bP[t], accP[s][t], 0, 0, 0);
        } else if (pAny) {
          const int cut = (rlo + fr) - (j0 + fk);     // keep e < cut  (j < i)
          bf16x8 ap = a;
#pragma unroll
          for (int e = 0; e < 8; ++e) if (e >= cut) ap[e] = (bf16_t)0.f;
#pragma unroll
          for (int t = 0; t < 2; ++t)
            accP[s][t] = __builtin_amdgcn_mfma_f32_16x16x32_bf16(ap, bP[t], accP[s][t], 0, 0, 0);
        }
        if (fFull) {
#pragma unroll
          for (int t = 0; t < 2; ++t)
            accF[s][t] = __builtin_amdgcn_mfma_f32_16x16x32_bf16(a, bF[t], accF[s][t], 0, 0, 0);
        } else if (fAny) {
          const int cut = (rlo + fr) - (j0 + fk);     // keep e > cut  (j > i)
          bf16x8 af = a;
#pragma unroll
          for (int e = 0; e < 8; ++e) if (e <= cut) af[e] = (bf16_t)0.f;
#pragma unroll
          for (int t = 0; t < 2; ++t)
            accF[s][t] = __builtin_amdgcn_mfma_f32_16x16x32_bf16(af, bF[t], accF[s][t], 0, 0, 0);
        }
      }
    }
    WAIT0(); BAR();
  }
#pragma unroll
  for (int s = 0; s < 2; ++s)
#pragma unroll
    for (int r = 0; r < 4; ++r) {
      const int row = i0 + mw + s * 16 + cr + r;
      const float spv = scaleP[b * SEQ + row];
      const float sfv = scaleF[b * SEQ + row];
#pragma unroll
      for (int t = 0; t < 2; ++t) {
        const int col = blockIdx.x * 64 + nw2 + t * 16 + cc;
        const size_t oi = ((size_t)b * SEQ + row) * HID + col;
        out[oi] = accP[s][t][r] * spv + accF[s][t][r] * sfv + out[oi];  // Gb already in out
      }
    }
}

extern "C" void kernel_launch(void* const* d_in, const int* in_sizes, int n_in,
                              void* d_out, int out_size, void* d_ws, size_t ws_size,
                              hipStream_t stream) {
  const float* F  = (const float*)d_in[0];
  const int*   sm = (const int*)  d_in[1];
  const float* W1 = (const float*)d_in[2];
  const float* b1 = (const float*)d_in[3];
  const float* W2 = (const float*)d_in[4];
  const float* b2 = (const float*)d_in[5];
  float* out = (float*)d_out;

  char* ws = (char*)d_ws;
  size_t off = 0;
  auto take = [&](size_t bytes) -> void* {
    void* p = ws + off;
    off += (bytes + 255) & ~(size_t)255;
    return p;
  };
  bf16_t* Fbf    = (bf16_t*)take((size_t)BATCH * SEQ * DIM * 2);   // 8 MB
  bf16_t* projbf = (bf16_t*)take((size_t)BATCH * SEQ * HID * 2);   // 8 MB
  bf16_t* GacT   = (bf16_t*)take((size_t)BATCH * SEQ * SEQ * 2);   // 16 MB
  bf16_t* Wpg    = (bf16_t*)take((size_t)1024 * 512 * 2);          // 1 MB
  bf16_t* W2ac   = (bf16_t*)take((size_t)1024 * 512 * 2);          // 1 MB
  float*  scaleP = (float*) take((size_t)BATCH * SEQ * 4);
  float*  scaleF = (float*) take((size_t)BATCH * SEQ * 4);

  const size_t wbytes = (size_t)SEQ * SEQ * 2;
  int chunk = (ws_size > off) ? (int)((ws_size - off) / wbytes) : 1;
  if (chunk > BATCH) chunk = BATCH;
  if (chunk < 1) chunk = 1;
  bf16_t* wbuf = (bf16_t*)(ws + off);

  prep_kernel<<<dim3(2568), dim3(256), 0, stream>>>(
      F, sm, W1, W2, Fbf, Wpg, W2ac, scaleP, scaleF);
  pg_mfma<<<dim3(1024 / 64, BATCH * SEQ / 128), dim3(256), 0, stream>>>(
      Fbf, Wpg, b1, b2, projbf, out);
  gact_mfma<<<dim3(SEQ / 64, SEQ / 128, BATCH), dim3(256), 0, stream>>>(
      W2ac, Fbf, sm, GacT);
  for (int b0 = 0; b0 < BATCH; b0 += chunk) {
    const int nb = (BATCH - b0 < chunk) ? (BATCH - b0) : chunk;
    weight_mfma<<<dim3(SEQ / 64, SEQ / 128, nb), dim3(256), 0, stream>>>(projbf, Fbf, wbuf, b0);
    tri_mfma<<<dim3(HID / 64, SEQ / 64, nb), dim3(256), 0, stream>>>(
        wbuf, GacT, scaleP, scaleF, out, b0);
  }
}

// Round 10
// 99.139 us; speedup vs baseline: 1.2271x; 1.1733x over previous
//
#include <hip/hip_runtime.h>

// PastFutureContext: B=8, N=1024, d=h=512 — bf16 MFMA, ring-3 counted vmcnt
// (r6 config = best measured, 107.3 µs), tri split into per-triangle segments
// with truncated j-ranges (stages only needed tiles; 24 KB LDS -> 6 blocks/CU).
// Math: out = sp_i*(trilW @ GaT^T) + sf_i*(triuW @ GcT^T) + Gb, where
//   W[b]    = proj[b] @ F[b]^T        (proj = F@W1^T + b1)
//   GacT[b] = [W2a;W2c] @ F[b]^T * sm_j
//   Gb      = F @ W2b^T + b2   — written straight into out (f32); tri does RMW.
// LDS swizzle (verified r5: conflicts=0): lane l stages global col-slot
// ((l&3)-(l>>3))&3; read slot q(r,c0)=(c0+(r>>1))&3.

constexpr int BATCH = 8;
constexpr int SEQ   = 1024;
constexpr int DIM   = 512;
constexpr int HID   = 512;

typedef __bf16 bf16_t;
typedef bf16_t bf16x8 __attribute__((ext_vector_type(8)));
typedef float  f32x4  __attribute__((ext_vector_type(4)));
typedef float  f4     __attribute__((ext_vector_type(4)));

typedef __attribute__((address_space(1))) void gv_t;
typedef __attribute__((address_space(3))) void lv_t;

__device__ __forceinline__ void gload16(const bf16_t* g, bf16_t* l) {
  __builtin_amdgcn_global_load_lds((gv_t*)g, (lv_t*)l, 16, 0, 0);
}

#define WAIT3() asm volatile("s_waitcnt vmcnt(3)" ::: "memory")
#define WAIT2() asm volatile("s_waitcnt vmcnt(2)" ::: "memory")
#define WAIT0() asm volatile("s_waitcnt vmcnt(0)" ::: "memory")
#define BAR()   { __builtin_amdgcn_s_barrier(); __builtin_amdgcn_sched_barrier(0); }

// Stage a [ROWS x 32] bf16 subtile (row-major, ld elems) into LDS as ROWS/16
// chunks of 512 elems; linear dest, pre-swizzled global source (see header).
template <int ROWS>
__device__ __forceinline__ void stage(const bf16_t* g, int ld, bf16_t* lds,
                                      int w, int lane) {
  const int r0 = lane >> 2;
  const int kc = ((((lane & 3) - (lane >> 3)) & 3)) * 8;
#pragma unroll
  for (int i = 0; i < ROWS / 64; ++i) {
    const int s = w * (ROWS / 64) + i;
    gload16(g + (size_t)(s * 16 + r0) * ld + kc, lds + s * 512);
  }
}

// read-side swizzled elem offset within a 16-row chunk (row fr, global slot c0)
__device__ __forceinline__ int swz8(int fr, int c0) {
  return (((fr << 2) | ((c0 + (fr >> 1)) & 3)) << 3);
}

// ---- fused prep: cvt F (blocks 0..2047) | prepw (2048..2559) | scales (2560..2567)
__global__ __launch_bounds__(256) void prep_kernel(
    const float* __restrict__ F, const int* __restrict__ smask,
    const float* __restrict__ W1, const float* __restrict__ W2,
    bf16_t* __restrict__ Fbf, bf16_t* __restrict__ Wpg, bf16_t* __restrict__ W2ac,
    float* __restrict__ sp, float* __restrict__ sf) {
  const int bid = blockIdx.x, tid = threadIdx.x;
  if (bid < 2048) {                       // cvt: 8 f32 -> bf16 per thread
    const int i = bid * 256 + tid;
    const f4* p = (const f4*)(F + (size_t)i * 8);
    f4 v0 = p[0], v1 = p[1];
    bf16x8 o;
    o[0] = (bf16_t)v0[0]; o[1] = (bf16_t)v0[1]; o[2] = (bf16_t)v0[2]; o[3] = (bf16_t)v0[3];
    o[4] = (bf16_t)v1[0]; o[5] = (bf16_t)v1[1]; o[6] = (bf16_t)v1[2]; o[7] = (bf16_t)v1[3];
    *(bf16x8*)(Fbf + (size_t)i * 8) = o;
    return;
  }
  if (bid < 2560) {                       // prepw: restack W1/W2 -> Wpg, W2ac
    const int idx = (bid - 2048) * 256 + tid;
    const int r = idx >> 6, c8 = (idx & 63) * 8;
    const float* src;
    bf16_t* dst;
    if (r < 512)       { src = W1 + (size_t)r * 512 + c8;                  dst = Wpg  + (size_t)r * 512 + c8; }
    else if (r < 1024) { src = W2 + (size_t)(r - 512) * 1536 + 512 + c8;   dst = Wpg  + (size_t)r * 512 + c8; }
    else if (r < 1536) { src = W2 + (size_t)(r - 1024) * 1536 + c8;        dst = W2ac + (size_t)(r - 1024) * 512 + c8; }
    else               { src = W2 + (size_t)(r - 1536) * 1536 + 1024 + c8; dst = W2ac + (size_t)(r - 1024) * 512 + c8; }
    f4 v0 = *(const f4*)src, v1 = *(const f4*)(src + 4);
    bf16x8 o;
    o[0] = (bf16_t)v0[0]; o[1] = (bf16_t)v0[1]; o[2] = (bf16_t)v0[2]; o[3] = (bf16_t)v0[3];
    o[4] = (bf16_t)v1[0]; o[5] = (bf16_t)v1[1]; o[6] = (bf16_t)v1[2]; o[7] = (bf16_t)v1[3];
    *(bf16x8*)dst = o;
    return;
  }
  // scales: batch = bid - 2560; 256 thr x 4 elems, wave scan + block combine
  const int b = bid - 2560;
  const int4 v4 = ((const int4*)(smask + b * SEQ))[tid];
  const int tsum = v4.x + v4.y + v4.z + v4.w;
  int x = tsum;
#pragma unroll
  for (int o = 1; o < 64; o <<= 1) {
    int y = __shfl_up(x, o, 64);
    if ((tid & 63) >= o) x += y;
  }
  __shared__ int wsum[4], wpre[5];
  if ((tid & 63) == 63) wsum[tid >> 6] = x;
  __syncthreads();
  if (tid == 0) { int c = 0; for (int w = 0; w < 4; ++w) { wpre[w] = c; c += wsum[w]; } wpre[4] = c; }
  __syncthreads();
  const int excl = (x - tsum) + wpre[tid >> 6];
  const float tot = (float)wpre[4];
  f4 spv, sfv;
  int pre = excl;
  const int e[4] = {v4.x, v4.y, v4.z, v4.w};
#pragma unroll
  for (int i = 0; i < 4; ++i) {
    const float P  = (float)pre;
    const float Fu = tot - (float)pre - (float)e[i];
    spv[i] = e[i] ? 1.f / (P  + 1e-8f) : 0.f;
    sfv[i] = e[i] ? 1.f / (Fu + 1e-8f) : 0.f;
    pre += e[i];
  }
  ((f4*)(sp + b * SEQ))[tid] = spv;
  ((f4*)(sf + b * SEQ))[tid] = sfv;
}

// ---- ring-3 counted-vmcnt 128x64 GEMM core (r6-verbatim, wave 64x32) ---------
__device__ __forceinline__ void gemm_ring(
    const bf16_t* __restrict__ A, int lda, const bf16_t* __restrict__ Bt, int ldb,
    int K, bf16_t* As, bf16_t* Bs, f32x4 acc[4][2],
    int w, int lane, int qoff, int mw, int nw) {
  const int NT = K / 32;
  stage<128>(A,       lda, As,        w, lane);
  stage<64>(Bt,       ldb, Bs,        w, lane);
  stage<128>(A + 32,  lda, As + 4096, w, lane);
  stage<64>(Bt + 32,  ldb, Bs + 2048, w, lane);
  WAIT3();
  BAR();
  int cur = 0;
  for (int k = 0; k < NT; ++k) {
    if (k + 2 < NT) {
      const int nx = (cur >= 1) ? cur - 1 : 2;          // (cur+2)%3
      stage<128>(A  + (k + 2) * 32, lda, As + nx * 4096, w, lane);
      stage<64>(Bt + (k + 2) * 32, ldb, Bs + nx * 2048, w, lane);
    }
    const bf16_t* ab = As + cur * 4096 + (mw >> 4) * 512 + qoff;
    const bf16_t* bb = Bs + cur * 2048 + (nw >> 4) * 512 + qoff;
    bf16x8 a[4], b[2];
#pragma unroll
    for (int s = 0; s < 4; ++s) a[s] = *(const bf16x8*)&ab[s * 512];
#pragma unroll
    for (int t = 0; t < 2; ++t) b[t] = *(const bf16x8*)&bb[t * 512];
#pragma unroll
    for (int s = 0; s < 4; ++s)
#pragma unroll
      for (int t = 0; t < 2; ++t)
        acc[s][t] = __builtin_amdgcn_mfma_f32_16x16x32_bf16(a[s], b[t], acc[s][t], 0, 0, 0);
    if (k + 1 < NT) {
      if (k + 2 < NT) { WAIT3(); } else { WAIT0(); }
      BAR();
    }
    cur = (cur == 2) ? 0 : cur + 1;
  }
}

#define TILE_IDS                                  \
  const int tid = threadIdx.x;                    \
  const int w = tid >> 6, lane = tid & 63;        \
  const int fr = lane & 15;                       \
  const int qoff = swz8(fr, lane >> 4);           \
  const int mw = (w >> 1) * 64, nw = (w & 1) * 32;\
  const int cr = (lane >> 4) * 4, cc = lane & 15;

// ---- pg: [proj | Gb] = F @ [W1;W2b]^T + [b1;b2]; Gb straight into out --------
__global__ __launch_bounds__(256) void pg_mfma(
    const bf16_t* __restrict__ Fbf, const bf16_t* __restrict__ Wpg,
    const float* __restrict__ b1, const float* __restrict__ b2,
    bf16_t* __restrict__ projbf, float* __restrict__ out) {
  __shared__ bf16_t As[3 * 4096], Bs[3 * 2048];
  TILE_IDS
  const int m0 = blockIdx.y * 128, n0 = blockIdx.x * 64;
  f32x4 acc[4][2] = {};
  gemm_ring(Fbf + (size_t)m0 * DIM, DIM, Wpg + (size_t)n0 * DIM, DIM, DIM,
            As, Bs, acc, w, lane, qoff, mw, nw);
  if (n0 < 512) {
#pragma unroll
    for (int s = 0; s < 4; ++s)
#pragma unroll
      for (int t = 0; t < 2; ++t) {
        const int col = n0 + nw + t * 16 + cc;
        const float bv = b1[col];
#pragma unroll
        for (int r = 0; r < 4; ++r)
          projbf[(size_t)(m0 + mw + s * 16 + cr + r) * HID + col] = (bf16_t)(acc[s][t][r] + bv);
      }
  } else {
#pragma unroll
    for (int s = 0; s < 4; ++s)
#pragma unroll
      for (int t = 0; t < 2; ++t) {
        const int col = (n0 - 512) + nw + t * 16 + cc;
        const float bv = b2[col];
#pragma unroll
        for (int r = 0; r < 4; ++r)
          out[(size_t)(m0 + mw + s * 16 + cr + r) * HID + col] = acc[s][t][r] + bv;
      }
  }
}

// ---- gact: GacT[b][m][j] = ([W2a;W2c] @ F[b]^T)[m][j] * sm_j ------------------
__global__ __launch_bounds__(256) void gact_mfma(
    const bf16_t* __restrict__ W2ac, const bf16_t* __restrict__ Fbf,
    const int* __restrict__ smask, bf16_t* __restrict__ GacT) {
  __shared__ bf16_t As[3 * 4096], Bs[3 * 2048];
  TILE_IDS
  const int b = blockIdx.z;
  const bf16_t* Bt = Fbf + (size_t)b * SEQ * DIM;
  const int m0 = blockIdx.y * 128, n0 = blockIdx.x * 64;
  f32x4 acc[4][2] = {};
  gemm_ring(W2ac + (size_t)m0 * DIM, DIM, Bt + (size_t)n0 * DIM, DIM, DIM,
            As, Bs, acc, w, lane, qoff, mw, nw);
  bf16_t* C = GacT + (size_t)b * SEQ * SEQ;
#pragma unroll
  for (int s = 0; s < 4; ++s)
#pragma unroll
    for (int t = 0; t < 2; ++t) {
      const int j = n0 + nw + t * 16 + cc;
      const float smj = (float)smask[b * SEQ + j];
#pragma unroll
      for (int r = 0; r < 4; ++r)
        C[(size_t)(m0 + mw + s * 16 + cr + r) * SEQ + j] = (bf16_t)(acc[s][t][r] * smj);
    }
}

// ---- weight[b] = proj[b] @ F[b]^T ---------------------------------------------
__global__ __launch_bounds__(256) void weight_mfma(
    const bf16_t* __restrict__ projbf, const bf16_t* __restrict__ Fbf,
    bf16_t* __restrict__ wbuf, int b0) {
  __shared__ bf16_t As[3 * 4096], Bs[3 * 2048];
  TILE_IDS
  const int b = b0 + blockIdx.z;
  const bf16_t* A  = projbf + (size_t)b * SEQ * DIM;
  const bf16_t* Bt = Fbf    + (size_t)b * SEQ * DIM;
  bf16_t* C = wbuf + (size_t)blockIdx.z * SEQ * SEQ;
  const int m0 = blockIdx.y * 128, n0 = blockIdx.x * 64;
  f32x4 acc[4][2] = {};
  gemm_ring(A + (size_t)m0 * DIM, DIM, Bt + (size_t)n0 * DIM, DIM, DIM,
            As, Bs, acc, w, lane, qoff, mw, nw);
#pragma unroll
  for (int s = 0; s < 4; ++s)
#pragma unroll
    for (int t = 0; t < 2; ++t)
#pragma unroll
      for (int r = 0; r < 4; ++r)
        C[(size_t)(m0 + mw + s * 16 + cr + r) * SEQ + n0 + nw + t * 16 + cc] = (bf16_t)acc[s][t][r];
}

// ---- tri — out += sp*(trilW @ GaT^T) + sf*(triuW @ GcT^T) ---------------------
// block 64(i) x 64(n); waves 2x2 (32x32). TWO sequential ring-3 segments:
//   seg1 PAST:   j-tiles [0, i0/32+2), stages A + GaTp only (2 loads/iter)
//   seg2 FUTURE: j-tiles [i0/32, 32),  stages A + GaTf only
// 24 KB LDS -> 6 blocks/CU; ~34 staged tiles/block vs 96 (r6 dual staging).
__global__ __launch_bounds__(256) void tri_mfma(
    const bf16_t* __restrict__ wbuf, const bf16_t* __restrict__ GacT,
    const float* __restrict__ scaleP, const float* __restrict__ scaleF,
    float* __restrict__ out, int b0) {
  __shared__ bf16_t As[3 * 2048], Bs[3 * 2048];
  const int tid = threadIdx.x;
  const int w = tid >> 6, lane = tid & 63;
  const int fr = lane & 15, fk = (lane >> 4) * 8;
  const int qoff = swz8(fr, lane >> 4);
  const int mw = (w >> 1) * 32, nw2 = (w & 1) * 32;
  const int cr = (lane >> 4) * 4, cc = lane & 15;
  const int b = b0 + blockIdx.z;
  const bf16_t* A    = wbuf + (size_t)blockIdx.z * SEQ * SEQ;
  const bf16_t* GaTp = GacT + (size_t)b * SEQ * SEQ + (size_t)(blockIdx.x * 64) * SEQ;
  const bf16_t* GaTf = GaTp + (size_t)512 * SEQ;
  const int i0 = blockIdx.y * 64;
  const bf16_t* Arow = A + (size_t)i0 * SEQ;
  f32x4 accP[2][2] = {}, accF[2][2] = {};

  // ---------------- segment 1: PAST (j < i), tiles [0, KP) ----------------
  {
    const int KP = (i0 >> 5) + 2;                 // last tile has j0 = i0+32
    stage<64>(Arow,      SEQ, As,        w, lane);
    stage<64>(GaTp,      SEQ, Bs,        w, lane);
    stage<64>(Arow + 32, SEQ, As + 2048, w, lane);
    stage<64>(GaTp + 32, SEQ, Bs + 2048, w, lane);
    WAIT2(); BAR();
    for (int kt = 0; kt < KP; ++kt) {
      const int cur = kt % 3;
      if (kt + 2 < KP) {
        const int nx = (kt + 2) % 3;
        stage<64>(Arow + (kt + 2) * 32, SEQ, As + nx * 2048, w, lane);
        stage<64>(GaTp + (kt + 2) * 32, SEQ, Bs + nx * 2048, w, lane);
      }
      const int j0 = kt * 32;
      if (j0 < i0 + mw + 31) {                     // wave has any past work
        const bf16_t* abase = As + cur * 2048 + (mw >> 4) * 512 + qoff;
        const bf16_t* bbase = Bs + cur * 2048 + (nw2 >> 4) * 512 + qoff;
        bf16x8 bP[2];
#pragma unroll
        for (int t = 0; t < 2; ++t) bP[t] = *(const bf16x8*)&bbase[t * 512];
#pragma unroll
        for (int s = 0; s < 2; ++s) {
          const int rlo = i0 + mw + s * 16;
          const bool pAny = (j0 < rlo + 15), pFull = (j0 + 31 < rlo);
          if (!pAny) continue;
          const bf16x8 a = *(const bf16x8*)&abase[s * 512];
          if (pFull) {
#pragma unroll
            for (int t = 0; t < 2; ++t)
              accP[s][t] = __builtin_amdgcn_mfma_f32_16x16x32_bf16(a, bP[t], accP[s][t], 0, 0, 0);
          } else {
            const int cut = (rlo + fr) - (j0 + fk);   // keep e < cut (j < i)
            bf16x8 ap = a;
#pragma unroll
            for (int e = 0; e < 8; ++e) if (e >= cut) ap[e] = (bf16_t)0.f;
#pragma unroll
            for (int t = 0; t < 2; ++t)
              accP[s][t] = __builtin_amdgcn_mfma_f32_16x16x32_bf16(ap, bP[t], accP[s][t], 0, 0, 0);
          }
        }
      }
      if (kt + 2 < KP)      { WAIT2(); BAR(); }
      else if (kt + 1 < KP) { WAIT0(); BAR(); }
    }
  }
  BAR();   // all waves done reading seg1 LDS before seg2 overwrites

  // ---------------- segment 2: FUTURE (j > i), tiles [KFs, 32) ----------------
  {
    const int KFs = i0 >> 5;                      // first tile with j0+31 > i0
    const int KF  = 32 - KFs;                     // >= 2 for all i0
    const bf16_t* A2 = Arow + KFs * 32;
    const bf16_t* B2 = GaTf + KFs * 32;
    stage<64>(A2,      SEQ, As,        w, lane);
    stage<64>(B2,      SEQ, Bs,        w, lane);
    stage<64>(A2 + 32, SEQ, As + 2048, w, lane);
    stage<64>(B2 + 32, SEQ, Bs + 2048, w, lane);
    WAIT2(); BAR();
    for (int kt = 0; kt < KF; ++kt) {
      const int cur = kt % 3;
      if (kt + 2 < KF) {
        const int nx = (kt + 2) % 3;
        stage<64>(A2 + (kt + 2) * 32, SEQ, As + nx * 2048, w, lane);
        stage<64>(B2 + (kt + 2) * 32, SEQ, Bs + nx * 2048, w, lane);
      }
      const int j0 = (KFs + kt) * 32;
      if (j0 + 31 > i0 + mw) {                     // wave has any future work
        const bf16_t* abase = As + cur * 2048 + (mw >> 4) * 512 + qoff;
        const bf16_t* bbase = Bs + cur * 2048 + (nw2 >> 4) * 512 + qoff;
        bf16x8 bF[2];
#pragma unroll
        for (int t = 0; t < 2; ++t) bF[t] = *(const bf16x8*)&bbase[t * 512];
#pragma unroll
        for (int s = 0; s < 2; ++s) {
          const int rlo = i0 + mw + s * 16;
          const bool fAny = (j0 + 31 > rlo), fFull = (j0 > rlo + 15);
          if (!fAny) continue;
          const bf16x8 a = *(const bf16x8*)&abase[s * 512];
          if (fFull) {
#pragma unroll
            for (int t = 0; t < 2; ++t)
              accF[s][t] = __builtin_amdgcn_mfma_f32_16x16x32_bf16(a, bF[t], accF[s][t], 0, 0, 0);
          } else {
            const int cut = (rlo + fr) - (j0 + fk);   // keep e > cut (j > i)
            bf16x8 af = a;
#pragma unroll
            for (int e = 0; e < 8; ++e) if (e <= cut) af[e] = (bf16_t)0.f;
#pragma unroll
            for (int t = 0; t < 2; ++t)
              accF[s][t] = __builtin_amdgcn_mfma_f32_16x16x32_bf16(af, bF[t], accF[s][t], 0, 0, 0);
          }
        }
      }
      if (kt + 2 < KF)      { WAIT2(); BAR(); }
      else if (kt + 1 < KF) { WAIT0(); BAR(); }
    }
  }

#pragma unroll
  for (int s = 0; s < 2; ++s)
#pragma unroll
    for (int r = 0; r < 4; ++r) {
      const int row = i0 + mw + s * 16 + cr + r;
      const float spv = scaleP[b * SEQ + row];
      const float sfv = scaleF[b * SEQ + row];
#pragma unroll
      for (int t = 0; t < 2; ++t) {
        const int col = blockIdx.x * 64 + nw2 + t * 16 + cc;
        const size_t oi = ((size_t)b * SEQ + row) * HID + col;
        out[oi] = accP[s][t][r] * spv + accF[s][t][r] * sfv + out[oi];  // Gb already in out
      }
    }
}

extern "C" void kernel_launch(void* const* d_in, const int* in_sizes, int n_in,
                              void* d_out, int out_size, void* d_ws, size_t ws_size,
                              hipStream_t stream) {
  const float* F  = (const float*)d_in[0];
  const int*   sm = (const int*)  d_in[1];
  const float* W1 = (const float*)d_in[2];
  const float* b1 = (const float*)d_in[3];
  const float* W2 = (const float*)d_in[4];
  const float* b2 = (const float*)d_in[5];
  float* out = (float*)d_out;

  char* ws = (char*)d_ws;
  size_t off = 0;
  auto take = [&](size_t bytes) -> void* {
    void* p = ws + off;
    off += (bytes + 255) & ~(size_t)255;
    return p;
  };
  bf16_t* Fbf    = (bf16_t*)take((size_t)BATCH * SEQ * DIM * 2);   // 8 MB
  bf16_t* projbf = (bf16_t*)take((size_t)BATCH * SEQ * HID * 2);   // 8 MB
  bf16_t* GacT   = (bf16_t*)take((size_t)BATCH * SEQ * SEQ * 2);   // 16 MB
  bf16_t* Wpg    = (bf16_t*)take((size_t)1024 * 512 * 2);          // 1 MB
  bf16_t* W2ac   = (bf16_t*)take((size_t)1024 * 512 * 2);          // 1 MB
  float*  scaleP = (float*) take((size_t)BATCH * SEQ * 4);
  float*  scaleF = (float*) take((size_t)BATCH * SEQ * 4);

  const size_t wbytes = (size_t)SEQ * SEQ * 2;
  int chunk = (ws_size > off) ? (int)((ws_size - off) / wbytes) : 1;
  if (chunk > BATCH) chunk = BATCH;
  if (chunk < 1) chunk = 1;
  bf16_t* wbuf = (bf16_t*)(ws + off);

  prep_kernel<<<dim3(2568), dim3(256), 0, stream>>>(
      F, sm, W1, W2, Fbf, Wpg, W2ac, scaleP, scaleF);
  pg_mfma<<<dim3(1024 / 64, BATCH * SEQ / 128), dim3(256), 0, stream>>>(
      Fbf, Wpg, b1, b2, projbf, out);
  gact_mfma<<<dim3(SEQ / 64, SEQ / 128, BATCH), dim3(256), 0, stream>>>(
      W2ac, Fbf, sm, GacT);
  for (int b0 = 0; b0 < BATCH; b0 += chunk) {
    const int nb = (BATCH - b0 < chunk) ? (BATCH - b0) : chunk;
    weight_mfma<<<dim3(SEQ / 64, SEQ / 128, nb), dim3(256), 0, stream>>>(projbf, Fbf, wbuf, b0);
    tri_mfma<<<dim3(HID / 64, SEQ / 64, nb), dim3(256), 0, stream>>>(
        wbuf, GacT, scaleP, scaleF, out, b0);
  }
}

// Round 11
// 87.609 us; speedup vs baseline: 1.3886x; 1.1316x over previous
//
#include <hip/hip_runtime.h>

// PastFutureContext: B=8, N=1024, d=h=512 — bf16 MFMA, ring-3 counted vmcnt.
// Round 11: union {pg ∪ gact} launch; batch->XCD affinity (b = lin%8) for
// gact/weight/tri so each batch's wbuf/GacT slice pins to one XCD L2.
// Math: out = sp_i*(trilW @ GaT^T) + sf_i*(triuW @ GcT^T) + Gb, where
//   W[b]    = proj[b] @ F[b]^T        (proj = F@W1^T + b1)
//   GacT[b] = [W2a;W2c] @ F[b]^T * sm_j
//   Gb      = F @ W2b^T + b2   — written straight into out (f32); tri does RMW.
// tri: two sequential ring-3 segments (past/future) with truncated j-ranges.
// LDS swizzle (verified r5: conflicts=0): lane l stages global col-slot
// ((l&3)-(l>>3))&3; read slot q(r,c0)=(c0+(r>>1))&3.

constexpr int BATCH = 8;
constexpr int SEQ   = 1024;
constexpr int DIM   = 512;
constexpr int HID   = 512;

typedef __bf16 bf16_t;
typedef bf16_t bf16x8 __attribute__((ext_vector_type(8)));
typedef float  f32x4  __attribute__((ext_vector_type(4)));
typedef float  f4     __attribute__((ext_vector_type(4)));

typedef __attribute__((address_space(1))) void gv_t;
typedef __attribute__((address_space(3))) void lv_t;

__device__ __forceinline__ void gload16(const bf16_t* g, bf16_t* l) {
  __builtin_amdgcn_global_load_lds((gv_t*)g, (lv_t*)l, 16, 0, 0);
}

#define WAIT3() asm volatile("s_waitcnt vmcnt(3)" ::: "memory")
#define WAIT2() asm volatile("s_waitcnt vmcnt(2)" ::: "memory")
#define WAIT0() asm volatile("s_waitcnt vmcnt(0)" ::: "memory")
#define BAR()   { __builtin_amdgcn_s_barrier(); __builtin_amdgcn_sched_barrier(0); }

// Stage a [ROWS x 32] bf16 subtile (row-major, ld elems) into LDS as ROWS/16
// chunks of 512 elems; linear dest, pre-swizzled global source (see header).
template <int ROWS>
__device__ __forceinline__ void stage(const bf16_t* g, int ld, bf16_t* lds,
                                      int w, int lane) {
  const int r0 = lane >> 2;
  const int kc = ((((lane & 3) - (lane >> 3)) & 3)) * 8;
#pragma unroll
  for (int i = 0; i < ROWS / 64; ++i) {
    const int s = w * (ROWS / 64) + i;
    gload16(g + (size_t)(s * 16 + r0) * ld + kc, lds + s * 512);
  }
}

// read-side swizzled elem offset within a 16-row chunk (row fr, global slot c0)
__device__ __forceinline__ int swz8(int fr, int c0) {
  return (((fr << 2) | ((c0 + (fr >> 1)) & 3)) << 3);
}

// ---- fused prep: cvt F (blocks 0..2047) | prepw (2048..2559) | scales (2560..2567)
__global__ __launch_bounds__(256) void prep_kernel(
    const float* __restrict__ F, const int* __restrict__ smask,
    const float* __restrict__ W1, const float* __restrict__ W2,
    bf16_t* __restrict__ Fbf, bf16_t* __restrict__ Wpg, bf16_t* __restrict__ W2ac,
    float* __restrict__ sp, float* __restrict__ sf) {
  const int bid = blockIdx.x, tid = threadIdx.x;
  if (bid < 2048) {                       // cvt: 8 f32 -> bf16 per thread
    const int i = bid * 256 + tid;
    const f4* p = (const f4*)(F + (size_t)i * 8);
    f4 v0 = p[0], v1 = p[1];
    bf16x8 o;
    o[0] = (bf16_t)v0[0]; o[1] = (bf16_t)v0[1]; o[2] = (bf16_t)v0[2]; o[3] = (bf16_t)v0[3];
    o[4] = (bf16_t)v1[0]; o[5] = (bf16_t)v1[1]; o[6] = (bf16_t)v1[2]; o[7] = (bf16_t)v1[3];
    *(bf16x8*)(Fbf + (size_t)i * 8) = o;
    return;
  }
  if (bid < 2560) {                       // prepw: restack W1/W2 -> Wpg, W2ac
    const int idx = (bid - 2048) * 256 + tid;
    const int r = idx >> 6, c8 = (idx & 63) * 8;
    const float* src;
    bf16_t* dst;
    if (r < 512)       { src = W1 + (size_t)r * 512 + c8;                  dst = Wpg  + (size_t)r * 512 + c8; }
    else if (r < 1024) { src = W2 + (size_t)(r - 512) * 1536 + 512 + c8;   dst = Wpg  + (size_t)r * 512 + c8; }
    else if (r < 1536) { src = W2 + (size_t)(r - 1024) * 1536 + c8;        dst = W2ac + (size_t)(r - 1024) * 512 + c8; }
    else               { src = W2 + (size_t)(r - 1536) * 1536 + 1024 + c8; dst = W2ac + (size_t)(r - 1024) * 512 + c8; }
    f4 v0 = *(const f4*)src, v1 = *(const f4*)(src + 4);
    bf16x8 o;
    o[0] = (bf16_t)v0[0]; o[1] = (bf16_t)v0[1]; o[2] = (bf16_t)v0[2]; o[3] = (bf16_t)v0[3];
    o[4] = (bf16_t)v1[0]; o[5] = (bf16_t)v1[1]; o[6] = (bf16_t)v1[2]; o[7] = (bf16_t)v1[3];
    *(bf16x8*)dst = o;
    return;
  }
  // scales: batch = bid - 2560; 256 thr x 4 elems, wave scan + block combine
  const int b = bid - 2560;
  const int4 v4 = ((const int4*)(smask + b * SEQ))[tid];
  const int tsum = v4.x + v4.y + v4.z + v4.w;
  int x = tsum;
#pragma unroll
  for (int o = 1; o < 64; o <<= 1) {
    int y = __shfl_up(x, o, 64);
    if ((tid & 63) >= o) x += y;
  }
  __shared__ int wsum[4], wpre[5];
  if ((tid & 63) == 63) wsum[tid >> 6] = x;
  __syncthreads();
  if (tid == 0) { int c = 0; for (int w = 0; w < 4; ++w) { wpre[w] = c; c += wsum[w]; } wpre[4] = c; }
  __syncthreads();
  const int excl = (x - tsum) + wpre[tid >> 6];
  const float tot = (float)wpre[4];
  f4 spv, sfv;
  int pre = excl;
  const int e[4] = {v4.x, v4.y, v4.z, v4.w};
#pragma unroll
  for (int i = 0; i < 4; ++i) {
    const float P  = (float)pre;
    const float Fu = tot - (float)pre - (float)e[i];
    spv[i] = e[i] ? 1.f / (P  + 1e-8f) : 0.f;
    sfv[i] = e[i] ? 1.f / (Fu + 1e-8f) : 0.f;
    pre += e[i];
  }
  ((f4*)(sp + b * SEQ))[tid] = spv;
  ((f4*)(sf + b * SEQ))[tid] = sfv;
}

// ---- ring-3 counted-vmcnt 128x64 GEMM core (r6-verbatim, wave 64x32) ---------
__device__ __forceinline__ void gemm_ring(
    const bf16_t* __restrict__ A, int lda, const bf16_t* __restrict__ Bt, int ldb,
    int K, bf16_t* As, bf16_t* Bs, f32x4 acc[4][2],
    int w, int lane, int qoff, int mw, int nw) {
  const int NT = K / 32;
  stage<128>(A,       lda, As,        w, lane);
  stage<64>(Bt,       ldb, Bs,        w, lane);
  stage<128>(A + 32,  lda, As + 4096, w, lane);
  stage<64>(Bt + 32,  ldb, Bs + 2048, w, lane);
  WAIT3();
  BAR();
  int cur = 0;
  for (int k = 0; k < NT; ++k) {
    if (k + 2 < NT) {
      const int nx = (cur >= 1) ? cur - 1 : 2;          // (cur+2)%3
      stage<128>(A  + (k + 2) * 32, lda, As + nx * 4096, w, lane);
      stage<64>(Bt + (k + 2) * 32, ldb, Bs + nx * 2048, w, lane);
    }
    const bf16_t* ab = As + cur * 4096 + (mw >> 4) * 512 + qoff;
    const bf16_t* bb = Bs + cur * 2048 + (nw >> 4) * 512 + qoff;
    bf16x8 a[4], b[2];
#pragma unroll
    for (int s = 0; s < 4; ++s) a[s] = *(const bf16x8*)&ab[s * 512];
#pragma unroll
    for (int t = 0; t < 2; ++t) b[t] = *(const bf16x8*)&bb[t * 512];
#pragma unroll
    for (int s = 0; s < 4; ++s)
#pragma unroll
      for (int t = 0; t < 2; ++t)
        acc[s][t] = __builtin_amdgcn_mfma_f32_16x16x32_bf16(a[s], b[t], acc[s][t], 0, 0, 0);
    if (k + 1 < NT) {
      if (k + 2 < NT) { WAIT3(); } else { WAIT0(); }
      BAR();
    }
    cur = (cur == 2) ? 0 : cur + 1;
  }
}

#define TILE_IDS                                  \
  const int tid = threadIdx.x;                    \
  const int w = tid >> 6, lane = tid & 63;        \
  const int fr = lane & 15;                       \
  const int qoff = swz8(fr, lane >> 4);           \
  const int mw = (w >> 1) * 64, nw = (w & 1) * 32;\
  const int cr = (lane >> 4) * 4, cc = lane & 15;

// ---- pgga union: bid<1024 -> pg; else gact (batch = q%8 for XCD affinity) ----
__global__ __launch_bounds__(256) void pgga_mfma(
    const bf16_t* __restrict__ Fbf, const bf16_t* __restrict__ Wpg,
    const bf16_t* __restrict__ W2ac, const int* __restrict__ smask,
    const float* __restrict__ b1, const float* __restrict__ b2,
    bf16_t* __restrict__ projbf, float* __restrict__ out,
    bf16_t* __restrict__ GacT) {
  __shared__ bf16_t As[3 * 4096], Bs[3 * 2048];
  TILE_IDS
  const int bid = blockIdx.x;
  f32x4 acc[4][2] = {};
  if (bid < 1024) {
    // pg: [proj | Gb] = F @ [W1;W2b]^T + [b1;b2]; Gb straight into out
    const int m0 = (bid >> 4) * 128, n0 = (bid & 15) * 64;
    gemm_ring(Fbf + (size_t)m0 * DIM, DIM, Wpg + (size_t)n0 * DIM, DIM, DIM,
              As, Bs, acc, w, lane, qoff, mw, nw);
    if (n0 < 512) {
#pragma unroll
      for (int s = 0; s < 4; ++s)
#pragma unroll
        for (int t = 0; t < 2; ++t) {
          const int col = n0 + nw + t * 16 + cc;
          const float bv = b1[col];
#pragma unroll
          for (int r = 0; r < 4; ++r)
            projbf[(size_t)(m0 + mw + s * 16 + cr + r) * HID + col] = (bf16_t)(acc[s][t][r] + bv);
        }
    } else {
#pragma unroll
      for (int s = 0; s < 4; ++s)
#pragma unroll
        for (int t = 0; t < 2; ++t) {
          const int col = (n0 - 512) + nw + t * 16 + cc;
          const float bv = b2[col];
#pragma unroll
          for (int r = 0; r < 4; ++r)
            out[(size_t)(m0 + mw + s * 16 + cr + r) * HID + col] = acc[s][t][r] + bv;
        }
    }
  } else {
    // gact: GacT[b][m][j] = ([W2a;W2c] @ F[b]^T)[m][j] * sm_j; b = q%8 (XCD)
    const int q = bid - 1024;
    const int b = q & 7, r7 = q >> 3;
    const int m0 = (r7 >> 4) * 128, n0 = (r7 & 15) * 64;
    const bf16_t* Bt = Fbf + (size_t)b * SEQ * DIM;
    gemm_ring(W2ac + (size_t)m0 * DIM, DIM, Bt + (size_t)n0 * DIM, DIM, DIM,
              As, Bs, acc, w, lane, qoff, mw, nw);
    bf16_t* C = GacT + (size_t)b * SEQ * SEQ;
#pragma unroll
    for (int s = 0; s < 4; ++s)
#pragma unroll
      for (int t = 0; t < 2; ++t) {
        const int j = n0 + nw + t * 16 + cc;
        const float smj = (float)smask[b * SEQ + j];
#pragma unroll
        for (int r = 0; r < 4; ++r)
          C[(size_t)(m0 + mw + s * 16 + cr + r) * SEQ + j] = (bf16_t)(acc[s][t][r] * smj);
      }
  }
}

// ---- weight[b] = proj[b] @ F[b]^T ; 1D grid, batch = lin%nb (XCD affinity) ---
__global__ __launch_bounds__(256) void weight_mfma(
    const bf16_t* __restrict__ projbf, const bf16_t* __restrict__ Fbf,
    bf16_t* __restrict__ wbuf, int b0, int nb) {
  __shared__ bf16_t As[3 * 4096], Bs[3 * 2048];
  TILE_IDS
  const int lin = blockIdx.x;
  const int bl = lin % nb, r7 = lin / nb;
  const int m0 = (r7 >> 4) * 128, n0 = (r7 & 15) * 64;
  const int b = b0 + bl;
  const bf16_t* A  = projbf + (size_t)b * SEQ * DIM;
  const bf16_t* Bt = Fbf    + (size_t)b * SEQ * DIM;
  bf16_t* C = wbuf + (size_t)bl * SEQ * SEQ;
  f32x4 acc[4][2] = {};
  gemm_ring(A + (size_t)m0 * DIM, DIM, Bt + (size_t)n0 * DIM, DIM, DIM,
            As, Bs, acc, w, lane, qoff, mw, nw);
#pragma unroll
  for (int s = 0; s < 4; ++s)
#pragma unroll
    for (int t = 0; t < 2; ++t)
#pragma unroll
      for (int r = 0; r < 4; ++r)
        C[(size_t)(m0 + mw + s * 16 + cr + r) * SEQ + n0 + nw + t * 16 + cc] = (bf16_t)acc[s][t][r];
}

// ---- tri — out += sp*(trilW @ GaT^T) + sf*(triuW @ GcT^T) ---------------------
// 1D grid, batch = lin%nb (XCD affinity); r = lin/nb: n0=(r&7)*64, i0=(r>>3)*64.
// Two sequential ring-3 segments with truncated j-ranges (r10 structure).
__global__ __launch_bounds__(256) void tri_mfma(
    const bf16_t* __restrict__ wbuf, const bf16_t* __restrict__ GacT,
    const float* __restrict__ scaleP, const float* __restrict__ scaleF,
    float* __restrict__ out, int b0, int nb) {
  __shared__ bf16_t As[3 * 2048], Bs[3 * 2048];
  const int tid = threadIdx.x;
  const int w = tid >> 6, lane = tid & 63;
  const int fr = lane & 15, fk = (lane >> 4) * 8;
  const int qoff = swz8(fr, lane >> 4);
  const int mw = (w >> 1) * 32, nw2 = (w & 1) * 32;
  const int cr = (lane >> 4) * 4, cc = lane & 15;
  const int lin = blockIdx.x;
  const int bl = lin % nb, r7 = lin / nb;
  const int n0 = (r7 & 7) * 64, i0 = (r7 >> 3) * 64;
  const int b = b0 + bl;
  const bf16_t* A    = wbuf + (size_t)bl * SEQ * SEQ;
  const bf16_t* GaTp = GacT + (size_t)b * SEQ * SEQ + (size_t)n0 * SEQ;
  const bf16_t* GaTf = GaTp + (size_t)512 * SEQ;
  const bf16_t* Arow = A + (size_t)i0 * SEQ;
  f32x4 accP[2][2] = {}, accF[2][2] = {};

  // ---------------- segment 1: PAST (j < i), tiles [0, KP) ----------------
  {
    const int KP = (i0 >> 5) + 2;                 // last tile has j0 = i0+32
    stage<64>(Arow,      SEQ, As,        w, lane);
    stage<64>(GaTp,      SEQ, Bs,        w, lane);
    stage<64>(Arow + 32, SEQ, As + 2048, w, lane);
    stage<64>(GaTp + 32, SEQ, Bs + 2048, w, lane);
    WAIT2(); BAR();
    for (int kt = 0; kt < KP; ++kt) {
      const int cur = kt % 3;
      if (kt + 2 < KP) {
        const int nx = (kt + 2) % 3;
        stage<64>(Arow + (kt + 2) * 32, SEQ, As + nx * 2048, w, lane);
        stage<64>(GaTp + (kt + 2) * 32, SEQ, Bs + nx * 2048, w, lane);
      }
      const int j0 = kt * 32;
      if (j0 < i0 + mw + 31) {                     // wave has any past work
        const bf16_t* abase = As + cur * 2048 + (mw >> 4) * 512 + qoff;
        const bf16_t* bbase = Bs + cur * 2048 + (nw2 >> 4) * 512 + qoff;
        bf16x8 bP[2];
#pragma unroll
        for (int t = 0; t < 2; ++t) bP[t] = *(const bf16x8*)&bbase[t * 512];
#pragma unroll
        for (int s = 0; s < 2; ++s) {
          const int rlo = i0 + mw + s * 16;
          const bool pAny = (j0 < rlo + 15), pFull = (j0 + 31 < rlo);
          if (!pAny) continue;
          const bf16x8 a = *(const bf16x8*)&abase[s * 512];
          if (pFull) {
#pragma unroll
            for (int t = 0; t < 2; ++t)
              accP[s][t] = __builtin_amdgcn_mfma_f32_16x16x32_bf16(a, bP[t], accP[s][t], 0, 0, 0);
          } else {
            const int cut = (rlo + fr) - (j0 + fk);   // keep e < cut (j < i)
            bf16x8 ap = a;
#pragma unroll
            for (int e = 0; e < 8; ++e) if (e >= cut) ap[e] = (bf16_t)0.f;
#pragma unroll
            for (int t = 0; t < 2; ++t)
              accP[s][t] = __builtin_amdgcn_mfma_f32_16x16x32_bf16(ap, bP[t], accP[s][t], 0, 0, 0);
          }
        }
      }
      if (kt + 2 < KP)      { WAIT2(); BAR(); }
      else if (kt + 1 < KP) { WAIT0(); BAR(); }
    }
  }
  BAR();   // all waves done reading seg1 LDS before seg2 overwrites

  // ---------------- segment 2: FUTURE (j > i), tiles [KFs, 32) ----------------
  {
    const int KFs = i0 >> 5;                      // first tile with j0+31 > i0
    const int KF  = 32 - KFs;                     // >= 2 for all i0
    const bf16_t* A2 = Arow + KFs * 32;
    const bf16_t* B2 = GaTf + KFs * 32;
    stage<64>(A2,      SEQ, As,        w, lane);
    stage<64>(B2,      SEQ, Bs,        w, lane);
    stage<64>(A2 + 32, SEQ, As + 2048, w, lane);
    stage<64>(B2 + 32, SEQ, Bs + 2048, w, lane);
    WAIT2(); BAR();
    for (int kt = 0; kt < KF; ++kt) {
      const int cur = kt % 3;
      if (kt + 2 < KF) {
        const int nx = (kt + 2) % 3;
        stage<64>(A2 + (kt + 2) * 32, SEQ, As + nx * 2048, w, lane);
        stage<64>(B2 + (kt + 2) * 32, SEQ, Bs + nx * 2048, w, lane);
      }
      const int j0 = (KFs + kt) * 32;
      if (j0 + 31 > i0 + mw) {                     // wave has any future work
        const bf16_t* abase = As + cur * 2048 + (mw >> 4) * 512 + qoff;
        const bf16_t* bbase = Bs + cur * 2048 + (nw2 >> 4) * 512 + qoff;
        bf16x8 bF[2];
#pragma unroll
        for (int t = 0; t < 2; ++t) bF[t] = *(const bf16x8*)&bbase[t * 512];
#pragma unroll
        for (int s = 0; s < 2; ++s) {
          const int rlo = i0 + mw + s * 16;
          const bool fAny = (j0 + 31 > rlo), fFull = (j0 > rlo + 15);
          if (!fAny) continue;
          const bf16x8 a = *(const bf16x8*)&abase[s * 512];
          if (fFull) {
#pragma unroll
            for (int t = 0; t < 2; ++t)
              accF[s][t] = __builtin_amdgcn_mfma_f32_16x16x32_bf16(a, bF[t], accF[s][t], 0, 0, 0);
          } else {
            const int cut = (rlo + fr) - (j0 + fk);   // keep e > cut (j > i)
            bf16x8 af = a;
#pragma unroll
            for (int e = 0; e < 8; ++e) if (e <= cut) af[e] = (bf16_t)0.f;
#pragma unroll
            for (int t = 0; t < 2; ++t)
              accF[s][t] = __builtin_amdgcn_mfma_f32_16x16x32_bf16(af, bF[t], accF[s][t], 0, 0, 0);
          }
        }
      }
      if (kt + 2 < KF)      { WAIT2(); BAR(); }
      else if (kt + 1 < KF) { WAIT0(); BAR(); }
    }
  }

#pragma unroll
  for (int s = 0; s < 2; ++s)
#pragma unroll
    for (int r = 0; r < 4; ++r) {
      const int row = i0 + mw + s * 16 + cr + r;
      const float spv = scaleP[b * SEQ + row];
      const float sfv = scaleF[b * SEQ + row];
#pragma unroll
      for (int t = 0; t < 2; ++t) {
        const int col = n0 + nw2 + t * 16 + cc;
        const size_t oi = ((size_t)b * SEQ + row) * HID + col;
        out[oi] = accP[s][t][r] * spv + accF[s][t][r] * sfv + out[oi];  // Gb already in out
      }
    }
}

extern "C" void kernel_launch(void* const* d_in, const int* in_sizes, int n_in,
                              void* d_out, int out_size, void* d_ws, size_t ws_size,
                              hipStream_t stream) {
  const float* F  = (const float*)d_in[0];
  const int*   sm = (const int*)  d_in[1];
  const float* W1 = (const float*)d_in[2];
  const float* b1 = (const float*)d_in[3];
  const float* W2 = (const float*)d_in[4];
  const float* b2 = (const float*)d_in[5];
  float* out = (float*)d_out;

  char* ws = (char*)d_ws;
  size_t off = 0;
  auto take = [&](size_t bytes) -> void* {
    void* p = ws + off;
    off += (bytes + 255) & ~(size_t)255;
    return p;
  };
  bf16_t* Fbf    = (bf16_t*)take((size_t)BATCH * SEQ * DIM * 2);   // 8 MB
  bf16_t* projbf = (bf16_t*)take((size_t)BATCH * SEQ * HID * 2);   // 8 MB
  bf16_t* GacT   = (bf16_t*)take((size_t)BATCH * SEQ * SEQ * 2);   // 16 MB
  bf16_t* Wpg    = (bf16_t*)take((size_t)1024 * 512 * 2);          // 1 MB
  bf16_t* W2ac   = (bf16_t*)take((size_t)1024 * 512 * 2);          // 1 MB
  float*  scaleP = (float*) take((size_t)BATCH * SEQ * 4);
  float*  scaleF = (float*) take((size_t)BATCH * SEQ * 4);

  const size_t wbytes = (size_t)SEQ * SEQ * 2;
  int chunk = (ws_size > off) ? (int)((ws_size - off) / wbytes) : 1;
  if (chunk > BATCH) chunk = BATCH;
  if (chunk < 1) chunk = 1;
  bf16_t* wbuf = (bf16_t*)(ws + off);

  prep_kernel<<<dim3(2568), dim3(256), 0, stream>>>(
      F, sm, W1, W2, Fbf, Wpg, W2ac, scaleP, scaleF);
  pgga_mfma<<<dim3(2048), dim3(256), 0, stream>>>(
      Fbf, Wpg, W2ac, sm, b1, b2, projbf, out, GacT);
  for (int b0 = 0; b0 < BATCH; b0 += chunk) {
    const int nb = (BATCH - b0 < chunk) ? (BATCH - b0) : chunk;
    weight_mfma<<<dim3(nb * 128), dim3(256), 0, stream>>>(projbf, Fbf, wbuf, b0, nb);
    tri_mfma<<<dim3(nb * 128), dim3(256), 0, stream>>>(
        wbuf, GacT, scaleP, scaleF, out, b0, nb);
  }
}

// Round 12
// 86.053 us; speedup vs baseline: 1.4137x; 1.0181x over previous
//
#include <hip/hip_runtime.h>

// PastFutureContext: B=8, N=1024, d=h=512 — bf16 MFMA, ring-3 counted vmcnt.
// Round 12: full batch->XCD affinity (pg too: b = bid&7) so projbf/Gb are
// written on the XCD that later reads them (weight/tri). Rest = r11 verbatim.
// Math: out = sp_i*(trilW @ GaT^T) + sf_i*(triuW @ GcT^T) + Gb, where
//   W[b]    = proj[b] @ F[b]^T        (proj = F@W1^T + b1)
//   GacT[b] = [W2a;W2c] @ F[b]^T * sm_j
//   Gb      = F @ W2b^T + b2   — written straight into out (f32); tri does RMW.
// tri: two sequential ring-3 segments (past/future) with truncated j-ranges.
// LDS swizzle (verified r5: conflicts=0): lane l stages global col-slot
// ((l&3)-(l>>3))&3; read slot q(r,c0)=(c0+(r>>1))&3.

constexpr int BATCH = 8;
constexpr int SEQ   = 1024;
constexpr int DIM   = 512;
constexpr int HID   = 512;

typedef __bf16 bf16_t;
typedef bf16_t bf16x8 __attribute__((ext_vector_type(8)));
typedef float  f32x4  __attribute__((ext_vector_type(4)));
typedef float  f4     __attribute__((ext_vector_type(4)));

typedef __attribute__((address_space(1))) void gv_t;
typedef __attribute__((address_space(3))) void lv_t;

__device__ __forceinline__ void gload16(const bf16_t* g, bf16_t* l) {
  __builtin_amdgcn_global_load_lds((gv_t*)g, (lv_t*)l, 16, 0, 0);
}

#define WAIT3() asm volatile("s_waitcnt vmcnt(3)" ::: "memory")
#define WAIT2() asm volatile("s_waitcnt vmcnt(2)" ::: "memory")
#define WAIT0() asm volatile("s_waitcnt vmcnt(0)" ::: "memory")
#define BAR()   { __builtin_amdgcn_s_barrier(); __builtin_amdgcn_sched_barrier(0); }

// Stage a [ROWS x 32] bf16 subtile (row-major, ld elems) into LDS as ROWS/16
// chunks of 512 elems; linear dest, pre-swizzled global source (see header).
template <int ROWS>
__device__ __forceinline__ void stage(const bf16_t* g, int ld, bf16_t* lds,
                                      int w, int lane) {
  const int r0 = lane >> 2;
  const int kc = ((((lane & 3) - (lane >> 3)) & 3)) * 8;
#pragma unroll
  for (int i = 0; i < ROWS / 64; ++i) {
    const int s = w * (ROWS / 64) + i;
    gload16(g + (size_t)(s * 16 + r0) * ld + kc, lds + s * 512);
  }
}

// read-side swizzled elem offset within a 16-row chunk (row fr, global slot c0)
__device__ __forceinline__ int swz8(int fr, int c0) {
  return (((fr << 2) | ((c0 + (fr >> 1)) & 3)) << 3);
}

// ---- fused prep: cvt F (blocks 0..2047) | prepw (2048..2559) | scales (2560..2567)
__global__ __launch_bounds__(256) void prep_kernel(
    const float* __restrict__ F, const int* __restrict__ smask,
    const float* __restrict__ W1, const float* __restrict__ W2,
    bf16_t* __restrict__ Fbf, bf16_t* __restrict__ Wpg, bf16_t* __restrict__ W2ac,
    float* __restrict__ sp, float* __restrict__ sf) {
  const int bid = blockIdx.x, tid = threadIdx.x;
  if (bid < 2048) {                       // cvt: 8 f32 -> bf16 per thread
    const int i = bid * 256 + tid;
    const f4* p = (const f4*)(F + (size_t)i * 8);
    f4 v0 = p[0], v1 = p[1];
    bf16x8 o;
    o[0] = (bf16_t)v0[0]; o[1] = (bf16_t)v0[1]; o[2] = (bf16_t)v0[2]; o[3] = (bf16_t)v0[3];
    o[4] = (bf16_t)v1[0]; o[5] = (bf16_t)v1[1]; o[6] = (bf16_t)v1[2]; o[7] = (bf16_t)v1[3];
    *(bf16x8*)(Fbf + (size_t)i * 8) = o;
    return;
  }
  if (bid < 2560) {                       // prepw: restack W1/W2 -> Wpg, W2ac
    const int idx = (bid - 2048) * 256 + tid;
    const int r = idx >> 6, c8 = (idx & 63) * 8;
    const float* src;
    bf16_t* dst;
    if (r < 512)       { src = W1 + (size_t)r * 512 + c8;                  dst = Wpg  + (size_t)r * 512 + c8; }
    else if (r < 1024) { src = W2 + (size_t)(r - 512) * 1536 + 512 + c8;   dst = Wpg  + (size_t)r * 512 + c8; }
    else if (r < 1536) { src = W2 + (size_t)(r - 1024) * 1536 + c8;        dst = W2ac + (size_t)(r - 1024) * 512 + c8; }
    else               { src = W2 + (size_t)(r - 1536) * 1536 + 1024 + c8; dst = W2ac + (size_t)(r - 1024) * 512 + c8; }
    f4 v0 = *(const f4*)src, v1 = *(const f4*)(src + 4);
    bf16x8 o;
    o[0] = (bf16_t)v0[0]; o[1] = (bf16_t)v0[1]; o[2] = (bf16_t)v0[2]; o[3] = (bf16_t)v0[3];
    o[4] = (bf16_t)v1[0]; o[5] = (bf16_t)v1[1]; o[6] = (bf16_t)v1[2]; o[7] = (bf16_t)v1[3];
    *(bf16x8*)dst = o;
    return;
  }
  // scales: batch = bid - 2560; 256 thr x 4 elems, wave scan + block combine
  const int b = bid - 2560;
  const int4 v4 = ((const int4*)(smask + b * SEQ))[tid];
  const int tsum = v4.x + v4.y + v4.z + v4.w;
  int x = tsum;
#pragma unroll
  for (int o = 1; o < 64; o <<= 1) {
    int y = __shfl_up(x, o, 64);
    if ((tid & 63) >= o) x += y;
  }
  __shared__ int wsum[4], wpre[5];
  if ((tid & 63) == 63) wsum[tid >> 6] = x;
  __syncthreads();
  if (tid == 0) { int c = 0; for (int w = 0; w < 4; ++w) { wpre[w] = c; c += wsum[w]; } wpre[4] = c; }
  __syncthreads();
  const int excl = (x - tsum) + wpre[tid >> 6];
  const float tot = (float)wpre[4];
  f4 spv, sfv;
  int pre = excl;
  const int e[4] = {v4.x, v4.y, v4.z, v4.w};
#pragma unroll
  for (int i = 0; i < 4; ++i) {
    const float P  = (float)pre;
    const float Fu = tot - (float)pre - (float)e[i];
    spv[i] = e[i] ? 1.f / (P  + 1e-8f) : 0.f;
    sfv[i] = e[i] ? 1.f / (Fu + 1e-8f) : 0.f;
    pre += e[i];
  }
  ((f4*)(sp + b * SEQ))[tid] = spv;
  ((f4*)(sf + b * SEQ))[tid] = sfv;
}

// ---- ring-3 counted-vmcnt 128x64 GEMM core (r6-verbatim, wave 64x32) ---------
__device__ __forceinline__ void gemm_ring(
    const bf16_t* __restrict__ A, int lda, const bf16_t* __restrict__ Bt, int ldb,
    int K, bf16_t* As, bf16_t* Bs, f32x4 acc[4][2],
    int w, int lane, int qoff, int mw, int nw) {
  const int NT = K / 32;
  stage<128>(A,       lda, As,        w, lane);
  stage<64>(Bt,       ldb, Bs,        w, lane);
  stage<128>(A + 32,  lda, As + 4096, w, lane);
  stage<64>(Bt + 32,  ldb, Bs + 2048, w, lane);
  WAIT3();
  BAR();
  int cur = 0;
  for (int k = 0; k < NT; ++k) {
    if (k + 2 < NT) {
      const int nx = (cur >= 1) ? cur - 1 : 2;          // (cur+2)%3
      stage<128>(A  + (k + 2) * 32, lda, As + nx * 4096, w, lane);
      stage<64>(Bt + (k + 2) * 32, ldb, Bs + nx * 2048, w, lane);
    }
    const bf16_t* ab = As + cur * 4096 + (mw >> 4) * 512 + qoff;
    const bf16_t* bb = Bs + cur * 2048 + (nw >> 4) * 512 + qoff;
    bf16x8 a[4], b[2];
#pragma unroll
    for (int s = 0; s < 4; ++s) a[s] = *(const bf16x8*)&ab[s * 512];
#pragma unroll
    for (int t = 0; t < 2; ++t) b[t] = *(const bf16x8*)&bb[t * 512];
#pragma unroll
    for (int s = 0; s < 4; ++s)
#pragma unroll
      for (int t = 0; t < 2; ++t)
        acc[s][t] = __builtin_amdgcn_mfma_f32_16x16x32_bf16(a[s], b[t], acc[s][t], 0, 0, 0);
    if (k + 1 < NT) {
      if (k + 2 < NT) { WAIT3(); } else { WAIT0(); }
      BAR();
    }
    cur = (cur == 2) ? 0 : cur + 1;
  }
}

#define TILE_IDS                                  \
  const int tid = threadIdx.x;                    \
  const int w = tid >> 6, lane = tid & 63;        \
  const int fr = lane & 15;                       \
  const int qoff = swz8(fr, lane >> 4);           \
  const int mw = (w >> 1) * 64, nw = (w & 1) * 32;\
  const int cr = (lane >> 4) * 4, cc = lane & 15;

// ---- pgga union: bid<1024 -> pg; else gact. Both batch-affine (b = x&7). ----
__global__ __launch_bounds__(256) void pgga_mfma(
    const bf16_t* __restrict__ Fbf, const bf16_t* __restrict__ Wpg,
    const bf16_t* __restrict__ W2ac, const int* __restrict__ smask,
    const float* __restrict__ b1, const float* __restrict__ b2,
    bf16_t* __restrict__ projbf, float* __restrict__ out,
    bf16_t* __restrict__ GacT) {
  __shared__ bf16_t As[3 * 4096], Bs[3 * 2048];
  TILE_IDS
  const int bid = blockIdx.x;
  f32x4 acc[4][2] = {};
  if (bid < 1024) {
    // pg: [proj | Gb] = F @ [W1;W2b]^T + [b1;b2]; Gb straight into out.
    // Affinity: b = bid&7 -> XCD b owns batch b's projbf / out rows.
    const int b = bid & 7;
    const int q = bid >> 3;                       // [0,128)
    const int m0 = b * 1024 + (q >> 4) * 128;     // rows of batch b
    const int n0 = (q & 15) * 64;
    gemm_ring(Fbf + (size_t)m0 * DIM, DIM, Wpg + (size_t)n0 * DIM, DIM, DIM,
              As, Bs, acc, w, lane, qoff, mw, nw);
    if (n0 < 512) {
#pragma unroll
      for (int s = 0; s < 4; ++s)
#pragma unroll
        for (int t = 0; t < 2; ++t) {
          const int col = n0 + nw + t * 16 + cc;
          const float bv = b1[col];
#pragma unroll
          for (int r = 0; r < 4; ++r)
            projbf[(size_t)(m0 + mw + s * 16 + cr + r) * HID + col] = (bf16_t)(acc[s][t][r] + bv);
        }
    } else {
#pragma unroll
      for (int s = 0; s < 4; ++s)
#pragma unroll
        for (int t = 0; t < 2; ++t) {
          const int col = (n0 - 512) + nw + t * 16 + cc;
          const float bv = b2[col];
#pragma unroll
          for (int r = 0; r < 4; ++r)
            out[(size_t)(m0 + mw + s * 16 + cr + r) * HID + col] = acc[s][t][r] + bv;
        }
    }
  } else {
    // gact: GacT[b][m][j] = ([W2a;W2c] @ F[b]^T)[m][j] * sm_j; b = q&7 (XCD)
    const int q = bid - 1024;
    const int b = q & 7, r7 = q >> 3;
    const int m0 = (r7 >> 4) * 128, n0 = (r7 & 15) * 64;
    const bf16_t* Bt = Fbf + (size_t)b * SEQ * DIM;
    gemm_ring(W2ac + (size_t)m0 * DIM, DIM, Bt + (size_t)n0 * DIM, DIM, DIM,
              As, Bs, acc, w, lane, qoff, mw, nw);
    bf16_t* C = GacT + (size_t)b * SEQ * SEQ;
#pragma unroll
    for (int s = 0; s < 4; ++s)
#pragma unroll
      for (int t = 0; t < 2; ++t) {
        const int j = n0 + nw + t * 16 + cc;
        const float smj = (float)smask[b * SEQ + j];
#pragma unroll
        for (int r = 0; r < 4; ++r)
          C[(size_t)(m0 + mw + s * 16 + cr + r) * SEQ + j] = (bf16_t)(acc[s][t][r] * smj);
      }
  }
}

// ---- weight[b] = proj[b] @ F[b]^T ; 1D grid, batch = lin%nb (XCD affinity) ---
__global__ __launch_bounds__(256) void weight_mfma(
    const bf16_t* __restrict__ projbf, const bf16_t* __restrict__ Fbf,
    bf16_t* __restrict__ wbuf, int b0, int nb) {
  __shared__ bf16_t As[3 * 4096], Bs[3 * 2048];
  TILE_IDS
  const int lin = blockIdx.x;
  const int bl = lin % nb, r7 = lin / nb;
  const int m0 = (r7 >> 4) * 128, n0 = (r7 & 15) * 64;
  const int b = b0 + bl;
  const bf16_t* A  = projbf + (size_t)b * SEQ * DIM;
  const bf16_t* Bt = Fbf    + (size_t)b * SEQ * DIM;
  bf16_t* C = wbuf + (size_t)bl * SEQ * SEQ;
  f32x4 acc[4][2] = {};
  gemm_ring(A + (size_t)m0 * DIM, DIM, Bt + (size_t)n0 * DIM, DIM, DIM,
            As, Bs, acc, w, lane, qoff, mw, nw);
#pragma unroll
  for (int s = 0; s < 4; ++s)
#pragma unroll
    for (int t = 0; t < 2; ++t)
#pragma unroll
      for (int r = 0; r < 4; ++r)
        C[(size_t)(m0 + mw + s * 16 + cr + r) * SEQ + n0 + nw + t * 16 + cc] = (bf16_t)acc[s][t][r];
}

// ---- tri — out += sp*(trilW @ GaT^T) + sf*(triuW @ GcT^T) ---------------------
// 1D grid, batch = lin%nb (XCD affinity); r = lin/nb: n0=(r&7)*64, i0=(r>>3)*64.
// Two sequential ring-3 segments with truncated j-ranges (r10 structure).
__global__ __launch_bounds__(256) void tri_mfma(
    const bf16_t* __restrict__ wbuf, const bf16_t* __restrict__ GacT,
    const float* __restrict__ scaleP, const float* __restrict__ scaleF,
    float* __restrict__ out, int b0, int nb) {
  __shared__ bf16_t As[3 * 2048], Bs[3 * 2048];
  const int tid = threadIdx.x;
  const int w = tid >> 6, lane = tid & 63;
  const int fr = lane & 15, fk = (lane >> 4) * 8;
  const int qoff = swz8(fr, lane >> 4);
  const int mw = (w >> 1) * 32, nw2 = (w & 1) * 32;
  const int cr = (lane >> 4) * 4, cc = lane & 15;
  const int lin = blockIdx.x;
  const int bl = lin % nb, r7 = lin / nb;
  const int n0 = (r7 & 7) * 64, i0 = (r7 >> 3) * 64;
  const int b = b0 + bl;
  const bf16_t* A    = wbuf + (size_t)bl * SEQ * SEQ;
  const bf16_t* GaTp = GacT + (size_t)b * SEQ * SEQ + (size_t)n0 * SEQ;
  const bf16_t* GaTf = GaTp + (size_t)512 * SEQ;
  const bf16_t* Arow = A + (size_t)i0 * SEQ;
  f32x4 accP[2][2] = {}, accF[2][2] = {};

  // ---------------- segment 1: PAST (j < i), tiles [0, KP) ----------------
  {
    const int KP = (i0 >> 5) + 2;                 // last tile has j0 = i0+32
    stage<64>(Arow,      SEQ, As,        w, lane);
    stage<64>(GaTp,      SEQ, Bs,        w, lane);
    stage<64>(Arow + 32, SEQ, As + 2048, w, lane);
    stage<64>(GaTp + 32, SEQ, Bs + 2048, w, lane);
    WAIT2(); BAR();
    for (int kt = 0; kt < KP; ++kt) {
      const int cur = kt % 3;
      if (kt + 2 < KP) {
        const int nx = (kt + 2) % 3;
        stage<64>(Arow + (kt + 2) * 32, SEQ, As + nx * 2048, w, lane);
        stage<64>(GaTp + (kt + 2) * 32, SEQ, Bs + nx * 2048, w, lane);
      }
      const int j0 = kt * 32;
      if (j0 < i0 + mw + 31) {                     // wave has any past work
        const bf16_t* abase = As + cur * 2048 + (mw >> 4) * 512 + qoff;
        const bf16_t* bbase = Bs + cur * 2048 + (nw2 >> 4) * 512 + qoff;
        bf16x8 bP[2];
#pragma unroll
        for (int t = 0; t < 2; ++t) bP[t] = *(const bf16x8*)&bbase[t * 512];
#pragma unroll
        for (int s = 0; s < 2; ++s) {
          const int rlo = i0 + mw + s * 16;
          const bool pAny = (j0 < rlo + 15), pFull = (j0 + 31 < rlo);
          if (!pAny) continue;
          const bf16x8 a = *(const bf16x8*)&abase[s * 512];
          if (pFull) {
#pragma unroll
            for (int t = 0; t < 2; ++t)
              accP[s][t] = __builtin_amdgcn_mfma_f32_16x16x32_bf16(a, bP[t], accP[s][t], 0, 0, 0);
          } else {
            const int cut = (rlo + fr) - (j0 + fk);   // keep e < cut (j < i)
            bf16x8 ap = a;
#pragma unroll
            for (int e = 0; e < 8; ++e) if (e >= cut) ap[e] = (bf16_t)0.f;
#pragma unroll
            for (int t = 0; t < 2; ++t)
              accP[s][t] = __builtin_amdgcn_mfma_f32_16x16x32_bf16(ap, bP[t], accP[s][t], 0, 0, 0);
          }
        }
      }
      if (kt + 2 < KP)      { WAIT2(); BAR(); }
      else if (kt + 1 < KP) { WAIT0(); BAR(); }
    }
  }
  BAR();   // all waves done reading seg1 LDS before seg2 overwrites

  // ---------------- segment 2: FUTURE (j > i), tiles [KFs, 32) ----------------
  {
    const int KFs = i0 >> 5;                      // first tile with j0+31 > i0
    const int KF  = 32 - KFs;                     // >= 2 for all i0
    const bf16_t* A2 = Arow + KFs * 32;
    const bf16_t* B2 = GaTf + KFs * 32;
    stage<64>(A2,      SEQ, As,        w, lane);
    stage<64>(B2,      SEQ, Bs,        w, lane);
    stage<64>(A2 + 32, SEQ, As + 2048, w, lane);
    stage<64>(B2 + 32, SEQ, Bs + 2048, w, lane);
    WAIT2(); BAR();
    for (int kt = 0; kt < KF; ++kt) {
      const int cur = kt % 3;
      if (kt + 2 < KF) {
        const int nx = (kt + 2) % 3;
        stage<64>(A2 + (kt + 2) * 32, SEQ, As + nx * 2048, w, lane);
        stage<64>(B2 + (kt + 2) * 32, SEQ, Bs + nx * 2048, w, lane);
      }
      const int j0 = (KFs + kt) * 32;
      if (j0 + 31 > i0 + mw) {                     // wave has any future work
        const bf16_t* abase = As + cur * 2048 + (mw >> 4) * 512 + qoff;
        const bf16_t* bbase = Bs + cur * 2048 + (nw2 >> 4) * 512 + qoff;
        bf16x8 bF[2];
#pragma unroll
        for (int t = 0; t < 2; ++t) bF[t] = *(const bf16x8*)&bbase[t * 512];
#pragma unroll
        for (int s = 0; s < 2; ++s) {
          const int rlo = i0 + mw + s * 16;
          const bool fAny = (j0 + 31 > rlo), fFull = (j0 > rlo + 15);
          if (!fAny) continue;
          const bf16x8 a = *(const bf16x8*)&abase[s * 512];
          if (fFull) {
#pragma unroll
            for (int t = 0; t < 2; ++t)
              accF[s][t] = __builtin_amdgcn_mfma_f32_16x16x32_bf16(a, bF[t], accF[s][t], 0, 0, 0);
          } else {
            const int cut = (rlo + fr) - (j0 + fk);   // keep e > cut (j > i)
            bf16x8 af = a;
#pragma unroll
            for (int e = 0; e < 8; ++e) if (e <= cut) af[e] = (bf16_t)0.f;
#pragma unroll
            for (int t = 0; t < 2; ++t)
              accF[s][t] = __builtin_amdgcn_mfma_f32_16x16x32_bf16(af, bF[t], accF[s][t], 0, 0, 0);
          }
        }
      }
      if (kt + 2 < KF)      { WAIT2(); BAR(); }
      else if (kt + 1 < KF) { WAIT0(); BAR(); }
    }
  }

#pragma unroll
  for (int s = 0; s < 2; ++s)
#pragma unroll
    for (int r = 0; r < 4; ++r) {
      const int row = i0 + mw + s * 16 + cr + r;
      const float spv = scaleP[b * SEQ + row];
      const float sfv = scaleF[b * SEQ + row];
#pragma unroll
      for (int t = 0; t < 2; ++t) {
        const int col = n0 + nw2 + t * 16 + cc;
        const size_t oi = ((size_t)b * SEQ + row) * HID + col;
        out[oi] = accP[s][t][r] * spv + accF[s][t][r] * sfv + out[oi];  // Gb already in out
      }
    }
}

extern "C" void kernel_launch(void* const* d_in, const int* in_sizes, int n_in,
                              void* d_out, int out_size, void* d_ws, size_t ws_size,
                              hipStream_t stream) {
  const float* F  = (const float*)d_in[0];
  const int*   sm = (const int*)  d_in[1];
  const float* W1 = (const float*)d_in[2];
  const float* b1 = (const float*)d_in[3];
  const float* W2 = (const float*)d_in[4];
  const float* b2 = (const float*)d_in[5];
  float* out = (float*)d_out;

  char* ws = (char*)d_ws;
  size_t off = 0;
  auto take = [&](size_t bytes) -> void* {
    void* p = ws + off;
    off += (bytes + 255) & ~(size_t)255;
    return p;
  };
  bf16_t* Fbf    = (bf16_t*)take((size_t)BATCH * SEQ * DIM * 2);   // 8 MB
  bf16_t* projbf = (bf16_t*)take((size_t)BATCH * SEQ * HID * 2);   // 8 MB
  bf16_t* GacT   = (bf16_t*)take((size_t)BATCH * SEQ * SEQ * 2);   // 16 MB
  bf16_t* Wpg    = (bf16_t*)take((size_t)1024 * 512 * 2);          // 1 MB
  bf16_t* W2ac   = (bf16_t*)take((size_t)1024 * 512 * 2);          // 1 MB
  float*  scaleP = (float*) take((size_t)BATCH * SEQ * 4);
  float*  scaleF = (float*) take((size_t)BATCH * SEQ * 4);

  const size_t wbytes = (size_t)SEQ * SEQ * 2;
  int chunk = (ws_size > off) ? (int)((ws_size - off) / wbytes) : 1;
  if (chunk > BATCH) chunk = BATCH;
  if (chunk < 1) chunk = 1;
  bf16_t* wbuf = (bf16_t*)(ws + off);

  prep_kernel<<<dim3(2568), dim3(256), 0, stream>>>(
      F, sm, W1, W2, Fbf, Wpg, W2ac, scaleP, scaleF);
  pgga_mfma<<<dim3(2048), dim3(256), 0, stream>>>(
      Fbf, Wpg, W2ac, sm, b1, b2, projbf, out, GacT);
  for (int b0 = 0; b0 < BATCH; b0 += chunk) {
    const int nb = (BATCH - b0 < chunk) ? (BATCH - b0) : chunk;
    weight_mfma<<<dim3(nb * 128), dim3(256), 0, stream>>>(projbf, Fbf, wbuf, b0, nb);
    tri_mfma<<<dim3(nb * 128), dim3(256), 0, stream>>>(
        wbuf, GacT, scaleP, scaleF, out, b0, nb);
  }
}